// Round 1
// baseline (1004.608 us; speedup 1.0000x reference)
//
#include <hip/hip_runtime.h>
#include <math.h>

#define BETA_C   0.99f
#define TOL_C    1e-4f
#define ACC_C    1e-3f   // early-accept: Newton step smaller than this -> done
#define BRK_C    2e-5f   // bracket-width accept: protects against bf16-tgt vs fp32-V
                         // inconsistency (root may not exist in [0,1]; without this,
                         // bisection spins to MAXIT on ~0.5% of samples)
#define MAXIT_C  1000
#define EPS_C    1e-3f
#define BN       65536
#define NN       32
#define HFD      25
#define HVD      128
#define KVD      8
#define G        16   // lanes per cooperative group
#define GPB      16   // groups per 256-thread block (k_setup; 2 samples/group)
#define SGPB     4    // groups per 64-thread block (k_solve)
#define NQBLK    2048 // persistent solver blocks (8/CU; queue-drained)

typedef __attribute__((ext_vector_type(8))) short bf16x8;  // 8 bf16 (4 VGPRs)
typedef __attribute__((ext_vector_type(4))) float f32x4;   // 4 fp32 acc

// wave-internal LDS ordering (groups live inside one wave; no block barrier
// inside the divergent solve loop).
__device__ __forceinline__ void wsync() {
    __builtin_amdgcn_wave_barrier();
    __threadfence_block();
    __builtin_amdgcn_wave_barrier();
}

__device__ __forceinline__ float sp_(float x) {
    return fmaxf(x, 0.f) + log1pf(expf(-fabsf(x)));
}
// fast softplus for the bf16 MFMA V-path (feeds bf16 rounding anyway)
__device__ __forceinline__ float spf_(float x) {
    return fmaxf(x, 0.f) + __logf(1.f + __expf(-fabsf(x)));
}
__device__ __forceinline__ void spsig_(float x, float& sp, float& sg) {
    float t = expf(-fabsf(x));
    sp = fmaxf(x, 0.f) + log1pf(t);
    float r = 1.f / (1.f + t);
    sg = (x >= 0.f) ? r : t * r;
}
__device__ __forceinline__ float sgn_(float d) {
    return (d > 0.f) ? 1.f : ((d < 0.f) ? -1.f : 0.f);
}
__device__ __forceinline__ unsigned short f2bf(float f) {   // RNE f32->bf16
    unsigned int u = __float_as_uint(f);
    u += 0x7FFFu + ((u >> 16) & 1u);
    return (unsigned short)(u >> 16);
}

// ---- swizzled per-wave LDS activation tiles (G4: XOR row bits into bank bits)
// abf: [16 rows][32 k] bf16, 64 B rows  -> swizzle ^((row&3)<<4)
// hbf: [16 rows][128 k] bf16, 256 B rows -> swizzle ^((row&7)<<4)
__device__ __forceinline__ void aw_st(unsigned short* aw, int row, int col, float v) {
    const int b = (row * 64 + col * 2) ^ ((row & 3) << 4);
    *(unsigned short*)((char*)aw + b) = f2bf(v);
}
__device__ __forceinline__ bf16x8 aw_ld(const unsigned short* aw, int row, int k) {
    const int b = (row * 64 + k * 2) ^ ((row & 3) << 4);
    return *(const bf16x8*)((const char*)aw + b);
}
__device__ __forceinline__ void hw_st(unsigned short* hw, int row, int col, float v) {
    const int b = (row * 256 + col * 2) ^ ((row & 7) << 4);
    *(unsigned short*)((char*)hw + b) = f2bf(v);
}
__device__ __forceinline__ bf16x8 hw_ld(const unsigned short* hw, int row, int k) {
    const int b = (row * 256 + k * 2) ^ ((row & 7) << 4);
    return *(const bf16x8*)((const char*)hw + b);
}

// ---------------------------------------------------------------------------
// paired TAN eval (k_solve): V(fxA*gA), V(fxB*gB) + derivatives, sharing all
// W2/W3 loads. h1q[k] = (h1A, dh1A, h1B, dh1B).  (fp32, unchanged)
__device__ __forceinline__ void veval2_tan(
    const int gl, const float (&uA)[8], const float (&uB)[8],
    const float gA, const float gB,
    float4* h1q, const float n2A, const float n2B,
    const float (&b1v)[8], const float (&b2v)[8], const float (&d0c)[8],
    const float* __restrict__ vW2, const float* __restrict__ vW3,
    float& VA, float& dVA, float& VB, float& dVB)
{
    const int k0 = gl * 8;
#pragma unroll
    for (int j = 0; j < 8; ++j) {
        const float preA = fmaf(gA, uA[j], b1v[j]);
        const float preB = fmaf(gB, uB[j], b1v[j]);
        float spA, sgA, spB, sgB;
        spsig_(preA, spA, sgA);
        spsig_(preB, spB, sgB);
        h1q[k0 + j] = make_float4(spA, sgA * uA[j], spB, sgB * uB[j]);
    }
    wsync();
    float aA[8], dA[8], aB[8], dB[8];
#pragma unroll
    for (int j = 0; j < 8; ++j) { aA[j] = 0.f; dA[j] = 0.f; aB[j] = 0.f; dB[j] = 0.f; }
#pragma unroll 2
    for (int k = 0; k < HVD; ++k) {
        const float4 q = h1q[k];                       // broadcast
        const float4 wa = *(const float4*)(vW2 + k * HVD + k0);
        const float4 wb = *(const float4*)(vW2 + k * HVD + k0 + 4);
        aA[0] = fmaf(q.x, wa.x, aA[0]); aA[1] = fmaf(q.x, wa.y, aA[1]);
        aA[2] = fmaf(q.x, wa.z, aA[2]); aA[3] = fmaf(q.x, wa.w, aA[3]);
        aA[4] = fmaf(q.x, wb.x, aA[4]); aA[5] = fmaf(q.x, wb.y, aA[5]);
        aA[6] = fmaf(q.x, wb.z, aA[6]); aA[7] = fmaf(q.x, wb.w, aA[7]);
        dA[0] = fmaf(q.y, wa.x, dA[0]); dA[1] = fmaf(q.y, wa.y, dA[1]);
        dA[2] = fmaf(q.y, wa.z, dA[2]); dA[3] = fmaf(q.y, wa.w, dA[3]);
        dA[4] = fmaf(q.y, wb.x, dA[4]); dA[5] = fmaf(q.y, wb.y, dA[5]);
        dA[6] = fmaf(q.y, wb.z, dA[6]); dA[7] = fmaf(q.y, wb.w, dA[7]);
        aB[0] = fmaf(q.z, wa.x, aB[0]); aB[1] = fmaf(q.z, wa.y, aB[1]);
        aB[2] = fmaf(q.z, wa.z, aB[2]); aB[3] = fmaf(q.z, wa.w, aB[3]);
        aB[4] = fmaf(q.z, wb.x, aB[4]); aB[5] = fmaf(q.z, wb.y, aB[5]);
        aB[6] = fmaf(q.z, wb.z, aB[6]); aB[7] = fmaf(q.z, wb.w, aB[7]);
        dB[0] = fmaf(q.w, wa.x, dB[0]); dB[1] = fmaf(q.w, wa.y, dB[1]);
        dB[2] = fmaf(q.w, wa.z, dB[2]); dB[3] = fmaf(q.w, wa.w, dB[3]);
        dB[4] = fmaf(q.w, wb.x, dB[4]); dB[5] = fmaf(q.w, wb.y, dB[5]);
        dB[6] = fmaf(q.w, wb.z, dB[6]); dB[7] = fmaf(q.w, wb.w, dB[7]);
    }
    wsync();
    float oA[KVD], pA[KVD], oB[KVD], pB[KVD];
#pragma unroll
    for (int c = 0; c < KVD; ++c) { oA[c] = 0.f; pA[c] = 0.f; oB[c] = 0.f; pB[c] = 0.f; }
#pragma unroll
    for (int j = 0; j < 8; ++j) {
        float h2A, sA; spsig_(aA[j] + b2v[j], h2A, sA);
        const float dh2A = sA * dA[j];
        float h2B, sB; spsig_(aB[j] + b2v[j], h2B, sB);
        const float dh2B = sB * dB[j];
        const float4 w3a = *(const float4*)(vW3 + (k0 + j) * KVD);
        const float4 w3b = *(const float4*)(vW3 + (k0 + j) * KVD + 4);
        oA[0] = fmaf(h2A, w3a.x, oA[0]); oA[1] = fmaf(h2A, w3a.y, oA[1]);
        oA[2] = fmaf(h2A, w3a.z, oA[2]); oA[3] = fmaf(h2A, w3a.w, oA[3]);
        oA[4] = fmaf(h2A, w3b.x, oA[4]); oA[5] = fmaf(h2A, w3b.y, oA[5]);
        oA[6] = fmaf(h2A, w3b.z, oA[6]); oA[7] = fmaf(h2A, w3b.w, oA[7]);
        pA[0] = fmaf(dh2A, w3a.x, pA[0]); pA[1] = fmaf(dh2A, w3a.y, pA[1]);
        pA[2] = fmaf(dh2A, w3a.z, pA[2]); pA[3] = fmaf(dh2A, w3a.w, pA[3]);
        pA[4] = fmaf(dh2A, w3b.x, pA[4]); pA[5] = fmaf(dh2A, w3b.y, pA[5]);
        pA[6] = fmaf(dh2A, w3b.z, pA[6]); pA[7] = fmaf(dh2A, w3b.w, pA[7]);
        oB[0] = fmaf(h2B, w3a.x, oB[0]); oB[1] = fmaf(h2B, w3a.y, oB[1]);
        oB[2] = fmaf(h2B, w3a.z, oB[2]); oB[3] = fmaf(h2B, w3a.w, oB[3]);
        oB[4] = fmaf(h2B, w3b.x, oB[4]); oB[5] = fmaf(h2B, w3b.y, oB[5]);
        oB[6] = fmaf(h2B, w3b.z, oB[6]); oB[7] = fmaf(h2B, w3b.w, oB[7]);
        pB[0] = fmaf(dh2B, w3a.x, pB[0]); pB[1] = fmaf(dh2B, w3a.y, pB[1]);
        pB[2] = fmaf(dh2B, w3a.z, pB[2]); pB[3] = fmaf(dh2B, w3a.w, pB[3]);
        pB[4] = fmaf(dh2B, w3b.x, pB[4]); pB[5] = fmaf(dh2B, w3b.y, pB[5]);
        pB[6] = fmaf(dh2B, w3b.z, pB[6]); pB[7] = fmaf(dh2B, w3b.w, pB[7]);
    }
#pragma unroll
    for (int m = 1; m < G; m <<= 1) {
#pragma unroll
        for (int c = 0; c < KVD; ++c) {
            oA[c] += __shfl_xor(oA[c], m);
            pA[c] += __shfl_xor(pA[c], m);
            oB[c] += __shfl_xor(oB[c], m);
            pB[c] += __shfl_xor(pB[c], m);
        }
    }
    float vvA = 0.f, dvA = 0.f, vvB = 0.f, dvB = 0.f;
#pragma unroll
    for (int c = 0; c < KVD; ++c) {
        const float eA = oA[c] + d0c[c];
        const float eB = oB[c] + d0c[c];
        vvA = fmaf(eA, eA, vvA);
        dvA = fmaf(eA, pA[c], dvA);
        vvB = fmaf(eB, eB, vvB);
        dvB = fmaf(eB, pB[c], dvB);
    }
    VA  = vvA + EPS_C * gA * gA * n2A;
    dVA = 2.f * dvA + 2.f * EPS_C * gA * n2A;
    VB  = vvB + EPS_C * gB * gB * n2B;
    dVB = 2.f * dvB + 2.f * EPS_C * gB * n2B;
}

// ---- h0 = V-MLP(0) : weight-only, one tiny block --------------------------
__global__ __launch_bounds__(128) void k_h0(
    const float* __restrict__ vb1, const float* __restrict__ vW2,
    const float* __restrict__ vb2, const float* __restrict__ vW3,
    const float* __restrict__ vb3, float* __restrict__ h0g)
{
    __shared__ float h1s[HVD];
    __shared__ float h2s[HVD];
    int j = threadIdx.x;
    h1s[j] = sp_(vb1[j]);
    __syncthreads();
    float a = vb2[j];
    for (int k = 0; k < HVD; ++k) a = fmaf(h1s[k], vW2[k * HVD + j], a);
    h2s[j] = sp_(a);
    __syncthreads();
    if (j < KVD) {
        float acc = vb3[j];
        for (int k = 0; k < HVD; ++k) acc = fmaf(h2s[k], vW3[k * KVD + j], acc);
        h0g[j] = acc;
    }
}

// ---- weight prep: V-net weights -> bf16 in MFMA B-fragment layout ---------
// B-frag (16x16x32): lane needs B[k][col] at col=l&15(+16n), k=8*(l>>4)+j(+32c)
// -> store transposed [col][k] so each fragment is one contiguous 16B load.
__global__ __launch_bounds__(256) void k_wprep(
    const float* __restrict__ vW1, const float* __restrict__ vW2,
    const float* __restrict__ vW3,
    unsigned short* __restrict__ w1b, unsigned short* __restrict__ w2b,
    unsigned short* __restrict__ w3b)
{
    const int t = blockIdx.x * 256 + threadIdx.x;
    const int nth = gridDim.x * 256;
    for (int i = t; i < HVD * NN; i += nth) {          // [128 col][32 k]
        const int col = i >> 5, k = i & 31;
        w1b[i] = f2bf(vW1[k * HVD + col]);
    }
    for (int i = t; i < HVD * HVD; i += nth) {         // [128 col][128 k]
        const int col = i >> 7, k = i & 127;
        w2b[i] = f2bf(vW2[k * HVD + col]);
    }
    for (int i = t; i < 16 * HVD; i += nth) {          // [16 col][128 k], cols 8..15 = 0
        const int c = i >> 7, k = i & 127;
        w3b[i] = (c < KVD) ? f2bf(vW3[k * KVD + c]) : (unsigned short)0;
    }
}

// ---- setup: f-net fp32 (verbatim), V-net via bf16 MFMA --------------------
// Per wave: 4 groups x 2 samples = 8 samples = 16 V-input rows (x,f per
// sample) -> exact M=16 for mfma_f32_16x16x32_bf16.  Rows: 4*(gi&3)+{x0,f0,x1,f1}.
// A-frags come from swizzled per-wave LDS tiles; B-frags from prepped global
// bf16 weights (L1-resident: 32KB w2b).  V precision only affects tgt/vfb/act
// (k_solve recomputes V in fp32 from fp32 out[]) -> ~0.5% tgt error, benign.
__global__ __launch_bounds__(256, 4) void k_setup(
    const float* __restrict__ x_g,
    const float* __restrict__ fW1, const float* __restrict__ fb1,
    const float* __restrict__ fW2, const float* __restrict__ fb2,
    const float* __restrict__ fW3, const float* __restrict__ fb3,
    const float* __restrict__ vb1, const float* __restrict__ vb2,
    const float* __restrict__ vb3,
    const unsigned short* __restrict__ w1b,
    const unsigned short* __restrict__ w2b,
    const unsigned short* __restrict__ w3b,
    const float* __restrict__ h0g,
    float* __restrict__ out,
    int* __restrict__ cnt, int* __restrict__ list, float* __restrict__ tgt,
    float* __restrict__ vfb)
{
    __shared__ float2 xs[GPB][NN + 1];                       // 4.2 KB (f-net x)
    __shared__ float fh1[GPB][HFD + 1];
    __shared__ float fh2[GPB][HFD + 1];
    __shared__ __align__(16) unsigned short abf[4][16 * 32]; // 4 KB  (Z rows bf16)
    __shared__ __align__(16) unsigned short hbf[4][16 * HVD];// 16 KB (h1/h2 reuse)
    __shared__ int wcnt[4];
    __shared__ int bbase;

    const int tid = threadIdx.x;
    const int gi = tid >> 4;          // group 0..15
    const int gl = tid & (G - 1);
    const int w  = tid >> 6;          // wave 0..3
    const int l  = tid & 63;
    const int q  = l >> 4;            // lane quad within wave (== gi & 3)
    const int cc = l & 15;
    const int sb = (blockIdx.x * GPB + gi) * 2;
    const int s0 = sb, s1 = sb + 1;
    unsigned short* aw = abf[w];
    unsigned short* hw = hbf[w];

    // ---- stage x (fp32 for f-net, bf16 rows for V A-operand) ----
    const float xa0 = x_g[(size_t)s0 * NN + gl];
    const float xa1 = x_g[(size_t)s0 * NN + gl + 16];
    const float xb0 = x_g[(size_t)s1 * NN + gl];
    const float xb1 = x_g[(size_t)s1 * NN + gl + 16];
    xs[gi][gl]      = make_float2(xa0, xb0);
    xs[gi][gl + 16] = make_float2(xa1, xb1);
    const int r0 = 4 * q;             // this group's base row in the wave tile
    aw_st(aw, r0,     gl,      xa0); aw_st(aw, r0,     gl + 16, xa1);
    aw_st(aw, r0 + 2, gl,      xb0); aw_st(aw, r0 + 2, gl + 16, xb1);
    wsync();

    // ---- f-net (fp32, feeds out[] directly -> keep precise sp_) ----
    float fA0, fA1, fB0, fB1;
#pragma unroll
    for (int si = 0; si < 2; ++si) {
        for (int uu = gl; uu < HFD; uu += G) {
            float a = fb1[uu];
#pragma unroll
            for (int i = 0; i < NN; ++i) {
                const float2 xv2 = xs[gi][i];
                const float xv = si ? xv2.y : xv2.x;
                a = fmaf(xv, fW1[i * HFD + uu], a);
            }
            fh1[gi][uu] = sp_(a);
        }
        wsync();
        for (int uu = gl; uu < HFD; uu += G) {
            float a = fb2[uu];
#pragma unroll
            for (int i = 0; i < HFD; ++i)
                a = fmaf(fh1[gi][i], fW2[i * HFD + uu], a);
            fh2[gi][uu] = sp_(a);
        }
        wsync();
        float fo0 = fb3[gl], fo1 = fb3[gl + 16];
#pragma unroll
        for (int i = 0; i < HFD; ++i) {
            const float h = fh2[gi][i];
            fo0 = fmaf(h, fW3[i * NN + gl], fo0);
            fo1 = fmaf(h, fW3[i * NN + gl + 16], fo1);
        }
        const int ss = si ? s1 : s0;
        out[(size_t)ss * NN + gl]      = fo0;
        out[(size_t)ss * NN + gl + 16] = fo1;
        aw_st(aw, r0 + 1 + 2 * si, gl,      fo0);
        aw_st(aw, r0 + 1 + 2 * si, gl + 16, fo1);
        if (si == 0) { fA0 = fo0; fA1 = fo1; } else { fB0 = fo0; fB1 = fo1; }
        wsync();
    }

    // ---- ||z||^2 per row (fp32 exact) ----
    float p0 = fmaf(xa0, xa0, xa1 * xa1);
    float p1 = fmaf(fA0, fA0, fA1 * fA1);
    float p2 = fmaf(xb0, xb0, xb1 * xb1);
    float p3 = fmaf(fB0, fB0, fB1 * fB1);
#pragma unroll
    for (int m = 1; m < G; m <<= 1) {
        p0 += __shfl_xor(p0, m); p1 += __shfl_xor(p1, m);
        p2 += __shfl_xor(p2, m); p3 += __shfl_xor(p3, m);
    }

    float b1v[8], b2v[8];
#pragma unroll
    for (int n = 0; n < 8; ++n) {
        b1v[n] = vb1[n * 16 + cc];    // col = n*16 + cc
        b2v[n] = vb2[n * 16 + cc];
    }

    const int kq = (l >> 4) * 8;      // this lane's k-offset within a K=32 chunk
    const f32x4 zf = {0.f, 0.f, 0.f, 0.f};

    // ---- V layer 1: u[16][128] = Z[16][32] @ W1  (8 MFMA, K=32 exact) ----
    const bf16x8 afr = aw_ld(aw, cc, kq);        // A: row=l&15, k=8*(l>>4)+j
    f32x4 acc1[8];
#pragma unroll
    for (int n = 0; n < 8; ++n) {
        const bf16x8 bfr = *(const bf16x8*)(w1b + (n * 16 + cc) * 32 + kq);
        acc1[n] = __builtin_amdgcn_mfma_f32_16x16x32_bf16(afr, bfr, zf, 0, 0, 0);
    }
    // h1 = softplus(u + b1) -> hbf (C layout: row=4q+r, col=n*16+cc)
#pragma unroll
    for (int n = 0; n < 8; ++n) {
#pragma unroll
        for (int r = 0; r < 4; ++r)
            hw_st(hw, r0 + r, n * 16 + cc, spf_(acc1[n][r] + b1v[n]));
    }
    wsync();

    // ---- V layer 2: a2[16][128] = H1 @ W2  (32 MFMA) ----
    f32x4 acc2[8];
#pragma unroll
    for (int n = 0; n < 8; ++n) acc2[n] = zf;
#pragma unroll
    for (int c = 0; c < 4; ++c) {
        const bf16x8 a2f = hw_ld(hw, cc, c * 32 + kq);
#pragma unroll
        for (int n = 0; n < 8; ++n) {
            const bf16x8 b2f = *(const bf16x8*)(w2b + (n * 16 + cc) * HVD + c * 32 + kq);
            acc2[n] = __builtin_amdgcn_mfma_f32_16x16x32_bf16(a2f, b2f, acc2[n], 0, 0, 0);
        }
    }
    wsync();   // all W2 A-reads done before overwriting hbf with h2
#pragma unroll
    for (int n = 0; n < 8; ++n) {
#pragma unroll
        for (int r = 0; r < 4; ++r)
            hw_st(hw, r0 + r, n * 16 + cc, spf_(acc2[n][r] + b2v[n]));
    }
    wsync();

    // ---- V layer 3: o[16][16] = H2 @ W3pad  (4 MFMA, cols 8..15 zero) ----
    f32x4 acc3 = zf;
#pragma unroll
    for (int c = 0; c < 4; ++c) {
        const bf16x8 a3f = hw_ld(hw, cc, c * 32 + kq);
        const bf16x8 b3f = *(const bf16x8*)(w3b + cc * HVD + c * 32 + kq);
        acc3 = __builtin_amdgcn_mfma_f32_16x16x32_bf16(a3f, b3f, acc3, 0, 0, 0);
    }

    // ---- finalize V per row; rows 4q+r belong to THIS group's samples ----
    const float d0 = (cc < KVD) ? (vb3[cc] - h0g[cc]) : 0.f;
    float s_[4];
#pragma unroll
    for (int r = 0; r < 4; ++r) {
        const float e = (cc < KVD) ? (acc3[r] + d0) : 0.f;  // zero pad lanes
        s_[r] = e * e;
    }
#pragma unroll
    for (int m = 1; m < G; m <<= 1) {
#pragma unroll
        for (int r = 0; r < 4; ++r) s_[r] += __shfl_xor(s_[r], m);
    }
    const float Vx0 = s_[0] + EPS_C * p0;
    const float Vf0 = s_[1] + EPS_C * p1;
    const float Vx1 = s_[2] + EPS_C * p2;
    const float Vf1 = s_[3] + EPS_C * p3;

    const float t0 = BETA_C * Vx0;
    const float t1 = BETA_C * Vx1;
    const bool act0 = (Vf0 - t0) > 0.f;        // group-uniform
    const bool act1 = (Vf1 - t1) > 0.f;

    const bool lead = (gl == 0 && act0) || (gl == 1 && act1);
    unsigned long long bal = __ballot(lead);
    const int lane = threadIdx.x & 63, wv = threadIdx.x >> 6;
    const int rank = __popcll(bal & ((1ull << lane) - 1ull));
    if (lane == 0) wcnt[wv] = __popcll(bal);
    __syncthreads();
    if (threadIdx.x == 0) {
        int tot = 0;
        for (int i = 0; i < 4; ++i) { int c = wcnt[i]; wcnt[i] = tot; tot += c; }
        bbase = atomicAdd(cnt, tot);
    }
    __syncthreads();
    if (lead) {
        const int p = bbase + wcnt[wv] + rank;
        list[p] = (gl == 0) ? s0 : s1;
        tgt[p]  = (gl == 0) ? t0 : t1;
        vfb[p]  = (gl == 0) ? Vf0 : Vf1;       // V(fhatx) — solver's V(1)
    }
}

// ---- solver: persistent groups, PAIRED samples + Newton early-accept ------
// Early-accept: when an in-bracket Newton step is smaller than ACC_C, the
// verification eval is skipped.  Bracket-width accept (BRK_C): since tgt is
// now computed in the bf16 MFMA path, a thin band of samples may have
// tgt > V_fp32(1) (no root in [0,1]); bisection then converges the bracket
// to ~1 without |V-t|<=TOL ever holding — accept once e2-e1 <= BRK_C
// (gamma within 2e-5 of the clamped solution; output error ~|fx|*2e-5).
__global__ __launch_bounds__(64, 2) void k_solve(
    const float* __restrict__ vW1, const float* __restrict__ vb1,
    const float* __restrict__ vW2, const float* __restrict__ vb2,
    const float* __restrict__ vW3, const float* __restrict__ vb3,
    const float* __restrict__ h0g,
    float* __restrict__ out,
    const int* __restrict__ cnt, const int* __restrict__ list,
    const float* __restrict__ tgt, const float* __restrict__ vfb,
    int* __restrict__ qhead)
{
    __shared__ __align__(16) float4 h1s[SGPB][HVD + 2];
    __shared__ __align__(16) float2 fxs[SGPB][NN + 2];

    const int gi = threadIdx.x >> 4;
    const int gl = threadIdx.x & (G - 1);
    const int n  = *cnt;
    float4* h1q = h1s[gi];
    float2* fxr = fxs[gi];
    const int lead = threadIdx.x & 48;

    const int k0 = gl * 8;
    float b1v[8], b2v[8], d0c[8];
    {
        const float4 a = *(const float4*)(vb1 + k0);
        const float4 b = *(const float4*)(vb1 + k0 + 4);
        b1v[0]=a.x; b1v[1]=a.y; b1v[2]=a.z; b1v[3]=a.w;
        b1v[4]=b.x; b1v[5]=b.y; b1v[6]=b.z; b1v[7]=b.w;
        const float4 c = *(const float4*)(vb2 + k0);
        const float4 d = *(const float4*)(vb2 + k0 + 4);
        b2v[0]=c.x; b2v[1]=c.y; b2v[2]=c.z; b2v[3]=c.w;
        b2v[4]=d.x; b2v[5]=d.y; b2v[6]=d.z; b2v[7]=d.w;
#pragma unroll
        for (int cix = 0; cix < KVD; ++cix) d0c[cix] = vb3[cix] - h0g[cix];
    }

    int sA, sB; float tgA, tgB, fA0, fA1, fB0, fB1, n2A, n2B;
    float uA[8], uB[8];
    float gA, e1A, e2A, vA1, vA2;
    float gB, e1B, e2B, vB1, vB2;
    bool pendA, doneA, pendB, doneB;
    int itA, itB;

    auto grab = [&]() -> bool {
        int v = 0;
        if (gl == 0) v = atomicAdd(qhead, 2);
        v = __shfl(v, lead);
        if (v >= n) return false;
        const bool hasB = (v + 1) < n;
        sA = list[v]; tgA = tgt[v];
        const float vfA = vfb[v];
        float vfB;
        if (hasB) { sB = list[v + 1]; tgB = tgt[v + 1]; vfB = vfb[v + 1]; }
        else      { sB = sA;          tgB = tgA;        vfB = vfA; }
        fA0 = out[(size_t)sA * NN + gl];
        fA1 = out[(size_t)sA * NN + gl + 16];
        fB0 = out[(size_t)sB * NN + gl];
        fB1 = out[(size_t)sB * NN + gl + 16];
        fxr[gl]      = make_float2(fA0, fB0);
        fxr[gl + 16] = make_float2(fA1, fB1);
        wsync();
        n2A = 0.f; n2B = 0.f;
#pragma unroll
        for (int i = 0; i < NN; ++i) {
            const float2 q = fxr[i];
            n2A = fmaf(q.x, q.x, n2A);
            n2B = fmaf(q.y, q.y, n2B);
        }
#pragma unroll
        for (int j = 0; j < 8; ++j) { uA[j] = 0.f; uB[j] = 0.f; }
#pragma unroll
        for (int i = 0; i < NN; ++i) {
            const float2 q = fxr[i];
            const float4 wa = *(const float4*)(vW1 + i * HVD + k0);
            const float4 wb = *(const float4*)(vW1 + i * HVD + k0 + 4);
            uA[0] = fmaf(q.x, wa.x, uA[0]); uA[1] = fmaf(q.x, wa.y, uA[1]);
            uA[2] = fmaf(q.x, wa.z, uA[2]); uA[3] = fmaf(q.x, wa.w, uA[3]);
            uA[4] = fmaf(q.x, wb.x, uA[4]); uA[5] = fmaf(q.x, wb.y, uA[5]);
            uA[6] = fmaf(q.x, wb.z, uA[6]); uA[7] = fmaf(q.x, wb.w, uA[7]);
            uB[0] = fmaf(q.y, wa.x, uB[0]); uB[1] = fmaf(q.y, wa.y, uB[1]);
            uB[2] = fmaf(q.y, wa.z, uB[2]); uB[3] = fmaf(q.y, wa.w, uB[3]);
            uB[4] = fmaf(q.y, wb.x, uB[4]); uB[5] = fmaf(q.y, wb.y, uB[5]);
            uB[6] = fmaf(q.y, wb.z, uB[6]); uB[7] = fmaf(q.y, wb.w, uB[7]);
        }
        gA = sqrtf(tgA / vfA); e1A = 0.f; e2A = 1.f; vA1 = 0.f; vA2 = vfA;
        gB = sqrtf(tgB / vfB); e1B = 0.f; e2B = 1.f; vB1 = 0.f; vB2 = vfB;
        pendA = false; doneA = false; itA = 0;
        pendB = false; doneB = !hasB; itB = 0;
        return true;
    };
    if (!grab()) return;

    auto step = [&](bool& done, bool& pend, float& gamma, float& e1, float& e2,
                    float& v_e1, float& v_e2, int& it,
                    const float vp, const float dv, const float target,
                    const int s, const float f0, const float f1) {
        if (done) return;
        if (pend) {
            const float sa = sgn_(vp - target);
            const float s1 = sgn_(v_e1 - target);
            const float s2 = sgn_(v_e2 - target);
            if (sa * s1 < 0.f) { e2 = gamma; v_e2 = vp; }
            if (sa * s2 < 0.f) { e1 = gamma; v_e1 = vp; }
            pend = false;
        }
        if (fabsf(vp - target) <= TOL_C || (e2 - e1) <= BRK_C) {
            out[(size_t)s * NN + gl]      = f0 * gamma;
            out[(size_t)s * NN + gl + 16] = f1 * gamma;
            done = true;
            return;
        }
        const float newt = gamma - (vp - target) / dv;
        if (newt >= e1 && newt <= e2) {       // NaN fails -> bisect
            if (fabsf(newt - gamma) <= ACC_C) {
                // early accept: skip verification eval (see kernel comment)
                out[(size_t)s * NN + gl]      = f0 * newt;
                out[(size_t)s * NN + gl + 16] = f1 * newt;
                done = true;
                return;
            }
            gamma = newt;
        } else {
            gamma = 0.5f * (e1 + e2);
            pend = true;
        }
        ++it;
        if (it >= MAXIT_C) {
            out[(size_t)s * NN + gl]      = f0 * gamma;
            out[(size_t)s * NN + gl + 16] = f1 * gamma;
            done = true;
        }
    };

    for (;;) {
        float vpA, dvA, vpB, dvB;
        veval2_tan(gl, uA, uB, gA, gB, h1q, n2A, n2B,
                   b1v, b2v, d0c, vW2, vW3, vpA, dvA, vpB, dvB);
        step(doneA, pendA, gA, e1A, e2A, vA1, vA2, itA, vpA, dvA, tgA, sA, fA0, fA1);
        step(doneB, pendB, gB, e1B, e2B, vB1, vB2, itB, vpB, dvB, tgB, sB, fB0, fB1);
        if (doneA && doneB) {
            if (!grab()) break;
        }
    }
}

extern "C" void kernel_launch(void* const* d_in, const int* in_sizes, int n_in,
                              void* d_out, int out_size, void* d_ws, size_t ws_size,
                              hipStream_t stream)
{
    const float* x   = (const float*)d_in[0];
    const float* fW1 = (const float*)d_in[1];
    const float* fb1 = (const float*)d_in[2];
    const float* fW2 = (const float*)d_in[3];
    const float* fb2 = (const float*)d_in[4];
    const float* fW3 = (const float*)d_in[5];
    const float* fb3 = (const float*)d_in[6];
    const float* vW1 = (const float*)d_in[7];
    const float* vb1 = (const float*)d_in[8];
    const float* vW2 = (const float*)d_in[9];
    const float* vb2 = (const float*)d_in[10];
    const float* vW3 = (const float*)d_in[11];
    const float* vb3 = (const float*)d_in[12];
    float* out = (float*)d_out;

    char* ws = (char*)d_ws;
    int*   cnt   = (int*)ws;                                 // 4 B
    int*   qhead = (int*)(ws + 4);                           // 4 B
    float* h0g   = (float*)(ws + 64);                        // 8 floats
    int*   list  = (int*)(ws + 128);                         // BN ints
    float* tgt   = (float*)(ws + 128 + (size_t)BN * 4);      // BN floats
    float* vfb   = (float*)(ws + 128 + (size_t)BN * 8);      // BN floats
    unsigned short* w1b = (unsigned short*)(ws + 128 + (size_t)BN * 12);  // 8 KB (16B-aligned)
    unsigned short* w2b = w1b + HVD * NN;                    // 32 KB
    unsigned short* w3b = w2b + HVD * HVD;                   // 4 KB

    hipMemsetAsync(ws, 0, 8, stream);                        // cnt + qhead

    hipLaunchKernelGGL(k_h0, dim3(1), dim3(HVD), 0, stream,
                       vb1, vW2, vb2, vW3, vb3, h0g);

    hipLaunchKernelGGL(k_wprep, dim3(32), dim3(256), 0, stream,
                       vW1, vW2, vW3, w1b, w2b, w3b);

    hipLaunchKernelGGL(k_setup, dim3(BN / (GPB * 2)), dim3(256), 0, stream,
                       x, fW1, fb1, fW2, fb2, fW3, fb3,
                       vb1, vb2, vb3, w1b, w2b, w3b,
                       h0g, out, cnt, list, tgt, vfb);

    hipLaunchKernelGGL(k_solve, dim3(NQBLK), dim3(64), 0, stream,
                       vW1, vb1, vW2, vb2, vW3, vb3,
                       h0g, out, cnt, list, tgt, vfb, qhead);
}

// Round 2
// 667.908 us; speedup vs baseline: 1.5041x; 1.5041x over previous
//
#include <hip/hip_runtime.h>
#include <math.h>

#define BETA_C   0.99f
#define TOL_C    1e-4f
#define ACC_C    1e-3f   // early-accept: Newton step smaller than this -> done
#define BRK_C    2e-5f   // bracket-width accept (bf16-tgt vs fp32-V: root may not exist)
#define FORCE_C  12      // after this many iters, force bisection (bracket ALWAYS
                         // contracts every eval -> hard bound ~29 evals/sample;
                         // kills the MAXIT tail that stretched R1 k_solve to 1000us
                         // at 8% VALUBusy)
#define MAXIT_C  1000
#define EPS_C    1e-3f
#define BN       65536
#define NN       32
#define HFD      25
#define HVD      128
#define KVD      8
#define G        16   // lanes per cooperative group
#define GPB      16   // groups per 256-thread block (k_setup; 2 samples/group)
#define SGPB     4    // groups per 64-thread block (k_solve)
#define NQBLK    2048 // persistent solver blocks (8/CU; queue-drained)

typedef __attribute__((ext_vector_type(8))) short bf16x8;  // 8 bf16 (4 VGPRs)
typedef __attribute__((ext_vector_type(4))) float f32x4;   // 4 fp32 acc

// wave-internal LDS ordering (groups live inside one wave; no block barrier
// inside the divergent solve loop).
__device__ __forceinline__ void wsync() {
    __builtin_amdgcn_wave_barrier();
    __threadfence_block();
    __builtin_amdgcn_wave_barrier();
}

__device__ __forceinline__ float sp_(float x) {
    return fmaxf(x, 0.f) + log1pf(expf(-fabsf(x)));
}
// fast softplus for the bf16 MFMA V-path (feeds bf16 rounding anyway)
__device__ __forceinline__ float spf_(float x) {
    return fmaxf(x, 0.f) + __logf(1.f + __expf(-fabsf(x)));
}
__device__ __forceinline__ void spsig_(float x, float& sp, float& sg) {
    float t = expf(-fabsf(x));
    sp = fmaxf(x, 0.f) + log1pf(t);
    float r = 1.f / (1.f + t);
    sg = (x >= 0.f) ? r : t * r;
}
__device__ __forceinline__ float sgn_(float d) {
    return (d > 0.f) ? 1.f : ((d < 0.f) ? -1.f : 0.f);
}
__device__ __forceinline__ unsigned short f2bf(float f) {   // RNE f32->bf16
    unsigned int u = __float_as_uint(f);
    u += 0x7FFFu + ((u >> 16) & 1u);
    return (unsigned short)(u >> 16);
}

// ---- swizzled per-wave LDS activation tiles (G4: XOR row bits into bank bits)
__device__ __forceinline__ void aw_st(unsigned short* aw, int row, int col, float v) {
    const int b = (row * 64 + col * 2) ^ ((row & 3) << 4);
    *(unsigned short*)((char*)aw + b) = f2bf(v);
}
__device__ __forceinline__ bf16x8 aw_ld(const unsigned short* aw, int row, int k) {
    const int b = (row * 64 + k * 2) ^ ((row & 3) << 4);
    return *(const bf16x8*)((const char*)aw + b);
}
__device__ __forceinline__ void hw_st(unsigned short* hw, int row, int col, float v) {
    const int b = (row * 256 + col * 2) ^ ((row & 7) << 4);
    *(unsigned short*)((char*)hw + b) = f2bf(v);
}
__device__ __forceinline__ bf16x8 hw_ld(const unsigned short* hw, int row, int k) {
    const int b = (row * 256 + k * 2) ^ ((row & 7) << 4);
    return *(const bf16x8*)((const char*)hw + b);
}

// ---------------------------------------------------------------------------
// paired TAN eval (k_solve): V(fxA*gA), V(fxB*gB) + derivatives, sharing all
// W2/W3 loads. h1q[k] = (h1A, dh1A, h1B, dh1B).  (fp32, unchanged)
__device__ __forceinline__ void veval2_tan(
    const int gl, const float (&uA)[8], const float (&uB)[8],
    const float gA, const float gB,
    float4* h1q, const float n2A, const float n2B,
    const float (&b1v)[8], const float (&b2v)[8], const float (&d0c)[8],
    const float* __restrict__ vW2, const float* __restrict__ vW3,
    float& VA, float& dVA, float& VB, float& dVB)
{
    const int k0 = gl * 8;
#pragma unroll
    for (int j = 0; j < 8; ++j) {
        const float preA = fmaf(gA, uA[j], b1v[j]);
        const float preB = fmaf(gB, uB[j], b1v[j]);
        float spA, sgA, spB, sgB;
        spsig_(preA, spA, sgA);
        spsig_(preB, spB, sgB);
        h1q[k0 + j] = make_float4(spA, sgA * uA[j], spB, sgB * uB[j]);
    }
    wsync();
    float aA[8], dA[8], aB[8], dB[8];
#pragma unroll
    for (int j = 0; j < 8; ++j) { aA[j] = 0.f; dA[j] = 0.f; aB[j] = 0.f; dB[j] = 0.f; }
#pragma unroll 2
    for (int k = 0; k < HVD; ++k) {
        const float4 q = h1q[k];                       // broadcast
        const float4 wa = *(const float4*)(vW2 + k * HVD + k0);
        const float4 wb = *(const float4*)(vW2 + k * HVD + k0 + 4);
        aA[0] = fmaf(q.x, wa.x, aA[0]); aA[1] = fmaf(q.x, wa.y, aA[1]);
        aA[2] = fmaf(q.x, wa.z, aA[2]); aA[3] = fmaf(q.x, wa.w, aA[3]);
        aA[4] = fmaf(q.x, wb.x, aA[4]); aA[5] = fmaf(q.x, wb.y, aA[5]);
        aA[6] = fmaf(q.x, wb.z, aA[6]); aA[7] = fmaf(q.x, wb.w, aA[7]);
        dA[0] = fmaf(q.y, wa.x, dA[0]); dA[1] = fmaf(q.y, wa.y, dA[1]);
        dA[2] = fmaf(q.y, wa.z, dA[2]); dA[3] = fmaf(q.y, wa.w, dA[3]);
        dA[4] = fmaf(q.y, wb.x, dA[4]); dA[5] = fmaf(q.y, wb.y, dA[5]);
        dA[6] = fmaf(q.y, wb.z, dA[6]); dA[7] = fmaf(q.y, wb.w, dA[7]);
        aB[0] = fmaf(q.z, wa.x, aB[0]); aB[1] = fmaf(q.z, wa.y, aB[1]);
        aB[2] = fmaf(q.z, wa.z, aB[2]); aB[3] = fmaf(q.z, wa.w, aB[3]);
        aB[4] = fmaf(q.z, wb.x, aB[4]); aB[5] = fmaf(q.z, wb.y, aB[5]);
        aB[6] = fmaf(q.z, wb.z, aB[6]); aB[7] = fmaf(q.z, wb.w, aB[7]);
        dB[0] = fmaf(q.w, wa.x, dB[0]); dB[1] = fmaf(q.w, wa.y, dB[1]);
        dB[2] = fmaf(q.w, wa.z, dB[2]); dB[3] = fmaf(q.w, wa.w, dB[3]);
        dB[4] = fmaf(q.w, wb.x, dB[4]); dB[5] = fmaf(q.w, wb.y, dB[5]);
        dB[6] = fmaf(q.w, wb.z, dB[6]); dB[7] = fmaf(q.w, wb.w, dB[7]);
    }
    wsync();
    float oA[KVD], pA[KVD], oB[KVD], pB[KVD];
#pragma unroll
    for (int c = 0; c < KVD; ++c) { oA[c] = 0.f; pA[c] = 0.f; oB[c] = 0.f; pB[c] = 0.f; }
#pragma unroll
    for (int j = 0; j < 8; ++j) {
        float h2A, sA; spsig_(aA[j] + b2v[j], h2A, sA);
        const float dh2A = sA * dA[j];
        float h2B, sB; spsig_(aB[j] + b2v[j], h2B, sB);
        const float dh2B = sB * dB[j];
        const float4 w3a = *(const float4*)(vW3 + (k0 + j) * KVD);
        const float4 w3b = *(const float4*)(vW3 + (k0 + j) * KVD + 4);
        oA[0] = fmaf(h2A, w3a.x, oA[0]); oA[1] = fmaf(h2A, w3a.y, oA[1]);
        oA[2] = fmaf(h2A, w3a.z, oA[2]); oA[3] = fmaf(h2A, w3a.w, oA[3]);
        oA[4] = fmaf(h2A, w3b.x, oA[4]); oA[5] = fmaf(h2A, w3b.y, oA[5]);
        oA[6] = fmaf(h2A, w3b.z, oA[6]); oA[7] = fmaf(h2A, w3b.w, oA[7]);
        pA[0] = fmaf(dh2A, w3a.x, pA[0]); pA[1] = fmaf(dh2A, w3a.y, pA[1]);
        pA[2] = fmaf(dh2A, w3a.z, pA[2]); pA[3] = fmaf(dh2A, w3a.w, pA[3]);
        pA[4] = fmaf(dh2A, w3b.x, pA[4]); pA[5] = fmaf(dh2A, w3b.y, pA[5]);
        pA[6] = fmaf(dh2A, w3b.z, pA[6]); pA[7] = fmaf(dh2A, w3b.w, pA[7]);
        oB[0] = fmaf(h2B, w3a.x, oB[0]); oB[1] = fmaf(h2B, w3a.y, oB[1]);
        oB[2] = fmaf(h2B, w3a.z, oB[2]); oB[3] = fmaf(h2B, w3a.w, oB[3]);
        oB[4] = fmaf(h2B, w3b.x, oB[4]); oB[5] = fmaf(h2B, w3b.y, oB[5]);
        oB[6] = fmaf(h2B, w3b.z, oB[6]); oB[7] = fmaf(h2B, w3b.w, oB[7]);
        pB[0] = fmaf(dh2B, w3a.x, pB[0]); pB[1] = fmaf(dh2B, w3a.y, pB[1]);
        pB[2] = fmaf(dh2B, w3a.z, pB[2]); pB[3] = fmaf(dh2B, w3a.w, pB[3]);
        pB[4] = fmaf(dh2B, w3b.x, pB[4]); pB[5] = fmaf(dh2B, w3b.y, pB[5]);
        pB[6] = fmaf(dh2B, w3b.z, pB[6]); pB[7] = fmaf(dh2B, w3b.w, pB[7]);
    }
#pragma unroll
    for (int m = 1; m < G; m <<= 1) {
#pragma unroll
        for (int c = 0; c < KVD; ++c) {
            oA[c] += __shfl_xor(oA[c], m);
            pA[c] += __shfl_xor(pA[c], m);
            oB[c] += __shfl_xor(oB[c], m);
            pB[c] += __shfl_xor(pB[c], m);
        }
    }
    float vvA = 0.f, dvA = 0.f, vvB = 0.f, dvB = 0.f;
#pragma unroll
    for (int c = 0; c < KVD; ++c) {
        const float eA = oA[c] + d0c[c];
        const float eB = oB[c] + d0c[c];
        vvA = fmaf(eA, eA, vvA);
        dvA = fmaf(eA, pA[c], dvA);
        vvB = fmaf(eB, eB, vvB);
        dvB = fmaf(eB, pB[c], dvB);
    }
    VA  = vvA + EPS_C * gA * gA * n2A;
    dVA = 2.f * dvA + 2.f * EPS_C * gA * n2A;
    VB  = vvB + EPS_C * gB * gB * n2B;
    dVB = 2.f * dvB + 2.f * EPS_C * gB * n2B;
}

// ---- h0 = V-MLP(0) : weight-only, one tiny block --------------------------
__global__ __launch_bounds__(128) void k_h0(
    const float* __restrict__ vb1, const float* __restrict__ vW2,
    const float* __restrict__ vb2, const float* __restrict__ vW3,
    const float* __restrict__ vb3, float* __restrict__ h0g)
{
    __shared__ float h1s[HVD];
    __shared__ float h2s[HVD];
    int j = threadIdx.x;
    h1s[j] = sp_(vb1[j]);
    __syncthreads();
    float a = vb2[j];
    for (int k = 0; k < HVD; ++k) a = fmaf(h1s[k], vW2[k * HVD + j], a);
    h2s[j] = sp_(a);
    __syncthreads();
    if (j < KVD) {
        float acc = vb3[j];
        for (int k = 0; k < HVD; ++k) acc = fmaf(h2s[k], vW3[k * KVD + j], acc);
        h0g[j] = acc;
    }
}

// ---- weight prep: V-net weights -> bf16 in MFMA B-fragment layout ---------
__global__ __launch_bounds__(256) void k_wprep(
    const float* __restrict__ vW1, const float* __restrict__ vW2,
    const float* __restrict__ vW3,
    unsigned short* __restrict__ w1b, unsigned short* __restrict__ w2b,
    unsigned short* __restrict__ w3b)
{
    const int t = blockIdx.x * 256 + threadIdx.x;
    const int nth = gridDim.x * 256;
    for (int i = t; i < HVD * NN; i += nth) {          // [128 col][32 k]
        const int col = i >> 5, k = i & 31;
        w1b[i] = f2bf(vW1[k * HVD + col]);
    }
    for (int i = t; i < HVD * HVD; i += nth) {         // [128 col][128 k]
        const int col = i >> 7, k = i & 127;
        w2b[i] = f2bf(vW2[k * HVD + col]);
    }
    for (int i = t; i < 16 * HVD; i += nth) {          // [16 col][128 k], cols 8..15 = 0
        const int c = i >> 7, k = i & 127;
        w3b[i] = (c < KVD) ? f2bf(vW3[k * KVD + c]) : (unsigned short)0;
    }
}

// ---- setup: f-net fp32 (verbatim), V-net via bf16 MFMA --------------------
__global__ __launch_bounds__(256, 4) void k_setup(
    const float* __restrict__ x_g,
    const float* __restrict__ fW1, const float* __restrict__ fb1,
    const float* __restrict__ fW2, const float* __restrict__ fb2,
    const float* __restrict__ fW3, const float* __restrict__ fb3,
    const float* __restrict__ vb1, const float* __restrict__ vb2,
    const float* __restrict__ vb3,
    const unsigned short* __restrict__ w1b,
    const unsigned short* __restrict__ w2b,
    const unsigned short* __restrict__ w3b,
    const float* __restrict__ h0g,
    float* __restrict__ out,
    int* __restrict__ cnt, int* __restrict__ list, float* __restrict__ tgt,
    float* __restrict__ vfb)
{
    __shared__ float2 xs[GPB][NN + 1];                       // 4.2 KB (f-net x)
    __shared__ float fh1[GPB][HFD + 1];
    __shared__ float fh2[GPB][HFD + 1];
    __shared__ __align__(16) unsigned short abf[4][16 * 32]; // 4 KB  (Z rows bf16)
    __shared__ __align__(16) unsigned short hbf[4][16 * HVD];// 16 KB (h1/h2 reuse)
    __shared__ int wcnt[4];
    __shared__ int bbase;

    const int tid = threadIdx.x;
    const int gi = tid >> 4;          // group 0..15
    const int gl = tid & (G - 1);
    const int w  = tid >> 6;          // wave 0..3
    const int l  = tid & 63;
    const int q  = l >> 4;            // lane quad within wave (== gi & 3)
    const int cc = l & 15;
    const int sb = (blockIdx.x * GPB + gi) * 2;
    const int s0 = sb, s1 = sb + 1;
    unsigned short* aw = abf[w];
    unsigned short* hw = hbf[w];

    // ---- stage x (fp32 for f-net, bf16 rows for V A-operand) ----
    const float xa0 = x_g[(size_t)s0 * NN + gl];
    const float xa1 = x_g[(size_t)s0 * NN + gl + 16];
    const float xb0 = x_g[(size_t)s1 * NN + gl];
    const float xb1 = x_g[(size_t)s1 * NN + gl + 16];
    xs[gi][gl]      = make_float2(xa0, xb0);
    xs[gi][gl + 16] = make_float2(xa1, xb1);
    const int r0 = 4 * q;             // this group's base row in the wave tile
    aw_st(aw, r0,     gl,      xa0); aw_st(aw, r0,     gl + 16, xa1);
    aw_st(aw, r0 + 2, gl,      xb0); aw_st(aw, r0 + 2, gl + 16, xb1);
    wsync();

    // ---- f-net (fp32, feeds out[] directly -> keep precise sp_) ----
    float fA0, fA1, fB0, fB1;
#pragma unroll
    for (int si = 0; si < 2; ++si) {
        for (int uu = gl; uu < HFD; uu += G) {
            float a = fb1[uu];
#pragma unroll
            for (int i = 0; i < NN; ++i) {
                const float2 xv2 = xs[gi][i];
                const float xv = si ? xv2.y : xv2.x;
                a = fmaf(xv, fW1[i * HFD + uu], a);
            }
            fh1[gi][uu] = sp_(a);
        }
        wsync();
        for (int uu = gl; uu < HFD; uu += G) {
            float a = fb2[uu];
#pragma unroll
            for (int i = 0; i < HFD; ++i)
                a = fmaf(fh1[gi][i], fW2[i * HFD + uu], a);
            fh2[gi][uu] = sp_(a);
        }
        wsync();
        float fo0 = fb3[gl], fo1 = fb3[gl + 16];
#pragma unroll
        for (int i = 0; i < HFD; ++i) {
            const float h = fh2[gi][i];
            fo0 = fmaf(h, fW3[i * NN + gl], fo0);
            fo1 = fmaf(h, fW3[i * NN + gl + 16], fo1);
        }
        const int ss = si ? s1 : s0;
        out[(size_t)ss * NN + gl]      = fo0;
        out[(size_t)ss * NN + gl + 16] = fo1;
        aw_st(aw, r0 + 1 + 2 * si, gl,      fo0);
        aw_st(aw, r0 + 1 + 2 * si, gl + 16, fo1);
        if (si == 0) { fA0 = fo0; fA1 = fo1; } else { fB0 = fo0; fB1 = fo1; }
        wsync();
    }

    // ---- ||z||^2 per row (fp32 exact) ----
    float p0 = fmaf(xa0, xa0, xa1 * xa1);
    float p1 = fmaf(fA0, fA0, fA1 * fA1);
    float p2 = fmaf(xb0, xb0, xb1 * xb1);
    float p3 = fmaf(fB0, fB0, fB1 * fB1);
#pragma unroll
    for (int m = 1; m < G; m <<= 1) {
        p0 += __shfl_xor(p0, m); p1 += __shfl_xor(p1, m);
        p2 += __shfl_xor(p2, m); p3 += __shfl_xor(p3, m);
    }

    float b1v[8], b2v[8];
#pragma unroll
    for (int n = 0; n < 8; ++n) {
        b1v[n] = vb1[n * 16 + cc];    // col = n*16 + cc
        b2v[n] = vb2[n * 16 + cc];
    }

    const int kq = (l >> 4) * 8;      // this lane's k-offset within a K=32 chunk
    const f32x4 zf = {0.f, 0.f, 0.f, 0.f};

    // ---- V layer 1: u[16][128] = Z[16][32] @ W1  (8 MFMA, K=32 exact) ----
    const bf16x8 afr = aw_ld(aw, cc, kq);        // A: row=l&15, k=8*(l>>4)+j
    f32x4 acc1[8];
#pragma unroll
    for (int n = 0; n < 8; ++n) {
        const bf16x8 bfr = *(const bf16x8*)(w1b + (n * 16 + cc) * 32 + kq);
        acc1[n] = __builtin_amdgcn_mfma_f32_16x16x32_bf16(afr, bfr, zf, 0, 0, 0);
    }
    // h1 = softplus(u + b1) -> hbf (C layout: row=4q+r, col=n*16+cc)
#pragma unroll
    for (int n = 0; n < 8; ++n) {
#pragma unroll
        for (int r = 0; r < 4; ++r)
            hw_st(hw, r0 + r, n * 16 + cc, spf_(acc1[n][r] + b1v[n]));
    }
    wsync();

    // ---- V layer 2: a2[16][128] = H1 @ W2  (32 MFMA) ----
    f32x4 acc2[8];
#pragma unroll
    for (int n = 0; n < 8; ++n) acc2[n] = zf;
#pragma unroll
    for (int c = 0; c < 4; ++c) {
        const bf16x8 a2f = hw_ld(hw, cc, c * 32 + kq);
#pragma unroll
        for (int n = 0; n < 8; ++n) {
            const bf16x8 b2f = *(const bf16x8*)(w2b + (n * 16 + cc) * HVD + c * 32 + kq);
            acc2[n] = __builtin_amdgcn_mfma_f32_16x16x32_bf16(a2f, b2f, acc2[n], 0, 0, 0);
        }
    }
    wsync();   // all W2 A-reads done before overwriting hbf with h2
#pragma unroll
    for (int n = 0; n < 8; ++n) {
#pragma unroll
        for (int r = 0; r < 4; ++r)
            hw_st(hw, r0 + r, n * 16 + cc, spf_(acc2[n][r] + b2v[n]));
    }
    wsync();

    // ---- V layer 3: o[16][16] = H2 @ W3pad  (4 MFMA, cols 8..15 zero) ----
    f32x4 acc3 = zf;
#pragma unroll
    for (int c = 0; c < 4; ++c) {
        const bf16x8 a3f = hw_ld(hw, cc, c * 32 + kq);
        const bf16x8 b3f = *(const bf16x8*)(w3b + cc * HVD + c * 32 + kq);
        acc3 = __builtin_amdgcn_mfma_f32_16x16x32_bf16(a3f, b3f, acc3, 0, 0, 0);
    }

    // ---- finalize V per row; rows 4q+r belong to THIS group's samples ----
    const float d0 = (cc < KVD) ? (vb3[cc] - h0g[cc]) : 0.f;
    float s_[4];
#pragma unroll
    for (int r = 0; r < 4; ++r) {
        const float e = (cc < KVD) ? (acc3[r] + d0) : 0.f;  // zero pad lanes
        s_[r] = e * e;
    }
#pragma unroll
    for (int m = 1; m < G; m <<= 1) {
#pragma unroll
        for (int r = 0; r < 4; ++r) s_[r] += __shfl_xor(s_[r], m);
    }
    const float Vx0 = s_[0] + EPS_C * p0;
    const float Vf0 = s_[1] + EPS_C * p1;
    const float Vx1 = s_[2] + EPS_C * p2;
    const float Vf1 = s_[3] + EPS_C * p3;

    const float t0 = BETA_C * Vx0;
    const float t1 = BETA_C * Vx1;
    const bool act0 = (Vf0 - t0) > 0.f;        // group-uniform
    const bool act1 = (Vf1 - t1) > 0.f;

    const bool lead = (gl == 0 && act0) || (gl == 1 && act1);
    unsigned long long bal = __ballot(lead);
    const int lane = threadIdx.x & 63, wv = threadIdx.x >> 6;
    const int rank = __popcll(bal & ((1ull << lane) - 1ull));
    if (lane == 0) wcnt[wv] = __popcll(bal);
    __syncthreads();
    if (threadIdx.x == 0) {
        int tot = 0;
        for (int i = 0; i < 4; ++i) { int c = wcnt[i]; wcnt[i] = tot; tot += c; }
        bbase = atomicAdd(cnt, tot);
    }
    __syncthreads();
    if (lead) {
        const int p = bbase + wcnt[wv] + rank;
        list[p] = (gl == 0) ? s0 : s1;
        tgt[p]  = (gl == 0) ? t0 : t1;
        vfb[p]  = (gl == 0) ? Vf0 : Vf1;       // V(fhatx) — solver's V(1)
    }
}

// ---- solver: persistent groups, PAIRED samples, SAFEGUARDED Newton --------
// R2 fix: the bracket is updated on EVERY eval (sign invariant s1*s2<0 holds
// from init and is preserved), and after FORCE_C iters we force pure
// bisection.  In-bracket Newton creep/ping-pong (which R1's pend-only bracket
// update let run to MAXIT=1000 -> 800us idle tail) is now bounded at
// ~FORCE_C + log2(1/BRK_C) ~ 29 evals/sample.
__global__ __launch_bounds__(64, 2) void k_solve(
    const float* __restrict__ vW1, const float* __restrict__ vb1,
    const float* __restrict__ vW2, const float* __restrict__ vb2,
    const float* __restrict__ vW3, const float* __restrict__ vb3,
    const float* __restrict__ h0g,
    float* __restrict__ out,
    const int* __restrict__ cnt, const int* __restrict__ list,
    const float* __restrict__ tgt, const float* __restrict__ vfb,
    int* __restrict__ qhead)
{
    __shared__ __align__(16) float4 h1s[SGPB][HVD + 2];
    __shared__ __align__(16) float2 fxs[SGPB][NN + 2];

    const int gi = threadIdx.x >> 4;
    const int gl = threadIdx.x & (G - 1);
    const int n  = *cnt;
    float4* h1q = h1s[gi];
    float2* fxr = fxs[gi];
    const int lead = threadIdx.x & 48;

    const int k0 = gl * 8;
    float b1v[8], b2v[8], d0c[8];
    {
        const float4 a = *(const float4*)(vb1 + k0);
        const float4 b = *(const float4*)(vb1 + k0 + 4);
        b1v[0]=a.x; b1v[1]=a.y; b1v[2]=a.z; b1v[3]=a.w;
        b1v[4]=b.x; b1v[5]=b.y; b1v[6]=b.z; b1v[7]=b.w;
        const float4 c = *(const float4*)(vb2 + k0);
        const float4 d = *(const float4*)(vb2 + k0 + 4);
        b2v[0]=c.x; b2v[1]=c.y; b2v[2]=c.z; b2v[3]=c.w;
        b2v[4]=d.x; b2v[5]=d.y; b2v[6]=d.z; b2v[7]=d.w;
#pragma unroll
        for (int cix = 0; cix < KVD; ++cix) d0c[cix] = vb3[cix] - h0g[cix];
    }

    int sA, sB; float tgA, tgB, fA0, fA1, fB0, fB1, n2A, n2B;
    float uA[8], uB[8];
    float gA, e1A, e2A, vA1, vA2;
    float gB, e1B, e2B, vB1, vB2;
    bool doneA, doneB;
    int itA, itB;

    auto grab = [&]() -> bool {
        int v = 0;
        if (gl == 0) v = atomicAdd(qhead, 2);
        v = __shfl(v, lead);
        if (v >= n) return false;
        const bool hasB = (v + 1) < n;
        sA = list[v]; tgA = tgt[v];
        const float vfA = vfb[v];
        float vfB;
        if (hasB) { sB = list[v + 1]; tgB = tgt[v + 1]; vfB = vfb[v + 1]; }
        else      { sB = sA;          tgB = tgA;        vfB = vfA; }
        fA0 = out[(size_t)sA * NN + gl];
        fA1 = out[(size_t)sA * NN + gl + 16];
        fB0 = out[(size_t)sB * NN + gl];
        fB1 = out[(size_t)sB * NN + gl + 16];
        fxr[gl]      = make_float2(fA0, fB0);
        fxr[gl + 16] = make_float2(fA1, fB1);
        wsync();
        n2A = 0.f; n2B = 0.f;
#pragma unroll
        for (int i = 0; i < NN; ++i) {
            const float2 q = fxr[i];
            n2A = fmaf(q.x, q.x, n2A);
            n2B = fmaf(q.y, q.y, n2B);
        }
#pragma unroll
        for (int j = 0; j < 8; ++j) { uA[j] = 0.f; uB[j] = 0.f; }
#pragma unroll
        for (int i = 0; i < NN; ++i) {
            const float2 q = fxr[i];
            const float4 wa = *(const float4*)(vW1 + i * HVD + k0);
            const float4 wb = *(const float4*)(vW1 + i * HVD + k0 + 4);
            uA[0] = fmaf(q.x, wa.x, uA[0]); uA[1] = fmaf(q.x, wa.y, uA[1]);
            uA[2] = fmaf(q.x, wa.z, uA[2]); uA[3] = fmaf(q.x, wa.w, uA[3]);
            uA[4] = fmaf(q.x, wb.x, uA[4]); uA[5] = fmaf(q.x, wb.y, uA[5]);
            uA[6] = fmaf(q.x, wb.z, uA[6]); uA[7] = fmaf(q.x, wb.w, uA[7]);
            uB[0] = fmaf(q.y, wa.x, uB[0]); uB[1] = fmaf(q.y, wa.y, uB[1]);
            uB[2] = fmaf(q.y, wa.z, uB[2]); uB[3] = fmaf(q.y, wa.w, uB[3]);
            uB[4] = fmaf(q.y, wb.x, uB[4]); uB[5] = fmaf(q.y, wb.y, uB[5]);
            uB[6] = fmaf(q.y, wb.z, uB[6]); uB[7] = fmaf(q.y, wb.w, uB[7]);
        }
        gA = sqrtf(tgA / vfA); e1A = 0.f; e2A = 1.f; vA1 = 0.f; vA2 = vfA;
        gB = sqrtf(tgB / vfB); e1B = 0.f; e2B = 1.f; vB1 = 0.f; vB2 = vfB;
        doneA = false; itA = 0;
        doneB = !hasB; itB = 0;
        return true;
    };
    if (!grab()) return;

    auto step = [&](bool& done, float& gamma, float& e1, float& e2,
                    float& v_e1, float& v_e2, int& it,
                    const float vp, const float dv, const float target,
                    const int s, const float f0, const float f1) {
        if (done) return;
        // accept: at tolerance, bracket collapsed, or iteration cap
        if (fabsf(vp - target) <= TOL_C || (e2 - e1) <= BRK_C) {
            out[(size_t)s * NN + gl]      = f0 * gamma;
            out[(size_t)s * NN + gl + 16] = f1 * gamma;
            done = true;
            return;
        }
        // ALWAYS contract the bracket with this eval.
        // Invariant: sign(v_e1-target) and sign(v_e2-target) are opposite
        // (init: v_e1=0<target, v_e2=vf>target; each update preserves it).
        const float sa = sgn_(vp - target);
        const float s1 = sgn_(v_e1 - target);
        if (sa * s1 < 0.f) { e2 = gamma; v_e2 = vp; }
        else               { e1 = gamma; v_e1 = vp; }
        ++it;
        const float newt = gamma - (vp - target) / dv;
        if (it < FORCE_C && newt >= e1 && newt <= e2) {   // NaN fails -> bisect
            if (fabsf(newt - gamma) <= ACC_C) {
                // early accept: skip verification eval
                out[(size_t)s * NN + gl]      = f0 * newt;
                out[(size_t)s * NN + gl + 16] = f1 * newt;
                done = true;
                return;
            }
            gamma = newt;
        } else {
            gamma = 0.5f * (e1 + e2);                     // guaranteed shrink
        }
        if (it >= MAXIT_C) {
            out[(size_t)s * NN + gl]      = f0 * gamma;
            out[(size_t)s * NN + gl + 16] = f1 * gamma;
            done = true;
        }
    };

    for (;;) {
        float vpA, dvA, vpB, dvB;
        veval2_tan(gl, uA, uB, gA, gB, h1q, n2A, n2B,
                   b1v, b2v, d0c, vW2, vW3, vpA, dvA, vpB, dvB);
        step(doneA, gA, e1A, e2A, vA1, vA2, itA, vpA, dvA, tgA, sA, fA0, fA1);
        step(doneB, gB, e1B, e2B, vB1, vB2, itB, vpB, dvB, tgB, sB, fB0, fB1);
        if (doneA && doneB) {
            if (!grab()) break;
        }
    }
}

extern "C" void kernel_launch(void* const* d_in, const int* in_sizes, int n_in,
                              void* d_out, int out_size, void* d_ws, size_t ws_size,
                              hipStream_t stream)
{
    const float* x   = (const float*)d_in[0];
    const float* fW1 = (const float*)d_in[1];
    const float* fb1 = (const float*)d_in[2];
    const float* fW2 = (const float*)d_in[3];
    const float* fb2 = (const float*)d_in[4];
    const float* fW3 = (const float*)d_in[5];
    const float* fb3 = (const float*)d_in[6];
    const float* vW1 = (const float*)d_in[7];
    const float* vb1 = (const float*)d_in[8];
    const float* vW2 = (const float*)d_in[9];
    const float* vb2 = (const float*)d_in[10];
    const float* vW3 = (const float*)d_in[11];
    const float* vb3 = (const float*)d_in[12];
    float* out = (float*)d_out;

    char* ws = (char*)d_ws;
    int*   cnt   = (int*)ws;                                 // 4 B
    int*   qhead = (int*)(ws + 4);                           // 4 B
    float* h0g   = (float*)(ws + 64);                        // 8 floats
    int*   list  = (int*)(ws + 128);                         // BN ints
    float* tgt   = (float*)(ws + 128 + (size_t)BN * 4);      // BN floats
    float* vfb   = (float*)(ws + 128 + (size_t)BN * 8);      // BN floats
    unsigned short* w1b = (unsigned short*)(ws + 128 + (size_t)BN * 12);  // 8 KB (16B-aligned)
    unsigned short* w2b = w1b + HVD * NN;                    // 32 KB
    unsigned short* w3b = w2b + HVD * HVD;                   // 4 KB

    hipMemsetAsync(ws, 0, 8, stream);                        // cnt + qhead

    hipLaunchKernelGGL(k_h0, dim3(1), dim3(HVD), 0, stream,
                       vb1, vW2, vb2, vW3, vb3, h0g);

    hipLaunchKernelGGL(k_wprep, dim3(32), dim3(256), 0, stream,
                       vW1, vW2, vW3, w1b, w2b, w3b);

    hipLaunchKernelGGL(k_setup, dim3(BN / (GPB * 2)), dim3(256), 0, stream,
                       x, fW1, fb1, fW2, fb2, fW3, fb3,
                       vb1, vb2, vb3, w1b, w2b, w3b,
                       h0g, out, cnt, list, tgt, vfb);

    hipLaunchKernelGGL(k_solve, dim3(NQBLK), dim3(64), 0, stream,
                       vW1, vb1, vW2, vb2, vW3, vb3,
                       h0g, out, cnt, list, tgt, vfb, qhead);
}

// Round 3
// 534.200 us; speedup vs baseline: 1.8806x; 1.2503x over previous
//
#include <hip/hip_runtime.h>
#include <math.h>

#define BETA_C   0.99f
#define TOL_C    1e-4f
#define ACC_C    1e-3f   // early-accept: Newton step smaller than this -> done
#define BRK_C    2e-4f   // bracket-width accept (gamma err 2e-4 -> out err ~1e-3*|fx|)
#define FORCE_C  6       // Newton gets 6 tries, then pure bisection (bracket
                         // contracts EVERY eval) -> hard bound ~6+log2(1/BRK)=18 evals
#define MAXIT_C  1000
#define EPS_C    1e-3f
#define BN       65536
#define NN       32
#define HFD      25
#define HVD      128
#define KVD      8
#define G        16   // lanes per cooperative group
#define GPB      16   // groups per 256-thread block (k_setup; 2 samples/group)
#define SGPB     4    // groups per 64-thread block (k_solve)
#define NQBLK    4096 // persistent solver blocks (16 waves/CU; queue-drained)

typedef __attribute__((ext_vector_type(8))) short bf16x8;  // 8 bf16 (4 VGPRs)
typedef __attribute__((ext_vector_type(8))) unsigned short u16x8;
typedef __attribute__((ext_vector_type(4))) float f32x4;   // 4 fp32 acc

// wave-internal LDS ordering (groups live inside one wave; no block barrier
// inside the divergent solve loop).
__device__ __forceinline__ void wsync() {
    __builtin_amdgcn_wave_barrier();
    __threadfence_block();
    __builtin_amdgcn_wave_barrier();
}

__device__ __forceinline__ float sp_(float x) {
    return fmaxf(x, 0.f) + log1pf(expf(-fabsf(x)));
}
// fast softplus for the bf16 MFMA V-path (feeds bf16 rounding anyway)
__device__ __forceinline__ float spf_(float x) {
    return fmaxf(x, 0.f) + __logf(1.f + __expf(-fabsf(x)));
}
__device__ __forceinline__ void spsig_(float x, float& sp, float& sg) {
    float t = expf(-fabsf(x));
    sp = fmaxf(x, 0.f) + log1pf(t);
    float r = 1.f / (1.f + t);
    sg = (x >= 0.f) ? r : t * r;
}
__device__ __forceinline__ float sgn_(float d) {
    return (d > 0.f) ? 1.f : ((d < 0.f) ? -1.f : 0.f);
}
__device__ __forceinline__ unsigned short f2bf(float f) {   // RNE f32->bf16
    unsigned int u = __float_as_uint(f);
    u += 0x7FFFu + ((u >> 16) & 1u);
    return (unsigned short)(u >> 16);
}
__device__ __forceinline__ float bf2f(unsigned short u) {
    return __uint_as_float(((unsigned int)u) << 16);
}

// ---- swizzled per-wave LDS activation tiles (G4: XOR row bits into bank bits)
__device__ __forceinline__ void aw_st(unsigned short* aw, int row, int col, float v) {
    const int b = (row * 64 + col * 2) ^ ((row & 3) << 4);
    *(unsigned short*)((char*)aw + b) = f2bf(v);
}
__device__ __forceinline__ bf16x8 aw_ld(const unsigned short* aw, int row, int k) {
    const int b = (row * 64 + k * 2) ^ ((row & 3) << 4);
    return *(const bf16x8*)((const char*)aw + b);
}
__device__ __forceinline__ void hw_st(unsigned short* hw, int row, int col, float v) {
    const int b = (row * 256 + col * 2) ^ ((row & 7) << 4);
    *(unsigned short*)((char*)hw + b) = f2bf(v);
}
__device__ __forceinline__ bf16x8 hw_ld(const unsigned short* hw, int row, int k) {
    const int b = (row * 256 + k * 2) ^ ((row & 7) << 4);
    return *(const bf16x8*)((const char*)hw + b);
}

// ---------------------------------------------------------------------------
// paired TAN eval (k_solve): V(fxA*gA), V(fxB*gB) + derivatives, sharing all
// W2/W3 loads.  R3: W2/W3 read as bf16 (w2s[k][col], w3s[k][c]) -> one
// ushort8 load/iter instead of 2x float4; 32KB W2 fits L1 (strong per-CU
// reuse).  Activations stay fp32 -> V(gamma) smooth, Newton/TOL unaffected.
// bf16 weights are MORE consistent with k_setup's bf16-MFMA tgt (R2's
// no-root grind band shrinks from ~0.5% to ~0.2% activation-rounding only).
__device__ __forceinline__ void veval2_tan(
    const int gl, const float (&uA)[8], const float (&uB)[8],
    const float gA, const float gB,
    float4* h1q, const float n2A, const float n2B,
    const float (&b1v)[8], const float (&b2v)[8], const float (&d0c)[8],
    const unsigned short* __restrict__ w2s, const unsigned short* __restrict__ w3s,
    float& VA, float& dVA, float& VB, float& dVB)
{
    const int k0 = gl * 8;
#pragma unroll
    for (int j = 0; j < 8; ++j) {
        const float preA = fmaf(gA, uA[j], b1v[j]);
        const float preB = fmaf(gB, uB[j], b1v[j]);
        float spA, sgA, spB, sgB;
        spsig_(preA, spA, sgA);
        spsig_(preB, spB, sgB);
        h1q[k0 + j] = make_float4(spA, sgA * uA[j], spB, sgB * uB[j]);
    }
    wsync();
    float aA[8], dA[8], aB[8], dB[8];
#pragma unroll
    for (int j = 0; j < 8; ++j) { aA[j] = 0.f; dA[j] = 0.f; aB[j] = 0.f; dB[j] = 0.f; }
#pragma unroll 2
    for (int k = 0; k < HVD; ++k) {
        const float4 q = h1q[k];                       // broadcast
        const u16x8 wv = *(const u16x8*)(w2s + k * HVD + k0);
        float w[8];
#pragma unroll
        for (int j = 0; j < 8; ++j) w[j] = bf2f(wv[j]);
#pragma unroll
        for (int j = 0; j < 8; ++j) {
            aA[j] = fmaf(q.x, w[j], aA[j]);
            dA[j] = fmaf(q.y, w[j], dA[j]);
            aB[j] = fmaf(q.z, w[j], aB[j]);
            dB[j] = fmaf(q.w, w[j], dB[j]);
        }
    }
    wsync();
    float oA[KVD], pA[KVD], oB[KVD], pB[KVD];
#pragma unroll
    for (int c = 0; c < KVD; ++c) { oA[c] = 0.f; pA[c] = 0.f; oB[c] = 0.f; pB[c] = 0.f; }
#pragma unroll
    for (int j = 0; j < 8; ++j) {
        float h2A, sA; spsig_(aA[j] + b2v[j], h2A, sA);
        const float dh2A = sA * dA[j];
        float h2B, sB; spsig_(aB[j] + b2v[j], h2B, sB);
        const float dh2B = sB * dB[j];
        const u16x8 w3v = *(const u16x8*)(w3s + (k0 + j) * KVD);
        float w3[8];
#pragma unroll
        for (int c = 0; c < 8; ++c) w3[c] = bf2f(w3v[c]);
#pragma unroll
        for (int c = 0; c < 8; ++c) {
            oA[c] = fmaf(h2A,  w3[c], oA[c]);
            pA[c] = fmaf(dh2A, w3[c], pA[c]);
            oB[c] = fmaf(h2B,  w3[c], oB[c]);
            pB[c] = fmaf(dh2B, w3[c], pB[c]);
        }
    }
#pragma unroll
    for (int m = 1; m < G; m <<= 1) {
#pragma unroll
        for (int c = 0; c < KVD; ++c) {
            oA[c] += __shfl_xor(oA[c], m);
            pA[c] += __shfl_xor(pA[c], m);
            oB[c] += __shfl_xor(oB[c], m);
            pB[c] += __shfl_xor(pB[c], m);
        }
    }
    float vvA = 0.f, dvA = 0.f, vvB = 0.f, dvB = 0.f;
#pragma unroll
    for (int c = 0; c < KVD; ++c) {
        const float eA = oA[c] + d0c[c];
        const float eB = oB[c] + d0c[c];
        vvA = fmaf(eA, eA, vvA);
        dvA = fmaf(eA, pA[c], dvA);
        vvB = fmaf(eB, eB, vvB);
        dvB = fmaf(eB, pB[c], dvB);
    }
    VA  = vvA + EPS_C * gA * gA * n2A;
    dVA = 2.f * dvA + 2.f * EPS_C * gA * n2A;
    VB  = vvB + EPS_C * gB * gB * n2B;
    dVB = 2.f * dvB + 2.f * EPS_C * gB * n2B;
}

// ---- h0 = V-MLP(0) : weight-only, one tiny block --------------------------
__global__ __launch_bounds__(128) void k_h0(
    const float* __restrict__ vb1, const float* __restrict__ vW2,
    const float* __restrict__ vb2, const float* __restrict__ vW3,
    const float* __restrict__ vb3, float* __restrict__ h0g)
{
    __shared__ float h1s[HVD];
    __shared__ float h2s[HVD];
    int j = threadIdx.x;
    h1s[j] = sp_(vb1[j]);
    __syncthreads();
    float a = vb2[j];
    for (int k = 0; k < HVD; ++k) a = fmaf(h1s[k], vW2[k * HVD + j], a);
    h2s[j] = sp_(a);
    __syncthreads();
    if (j < KVD) {
        float acc = vb3[j];
        for (int k = 0; k < HVD; ++k) acc = fmaf(h2s[k], vW3[k * KVD + j], acc);
        h0g[j] = acc;
    }
}

// ---- weight prep: V-net weights -> bf16 ------------------------------------
// w1b/w2b/w3b: MFMA B-fragment layout (transposed [col][k]) for k_setup.
// w2s/w3s: source layout [k][col] bf16 for the scalar solver (ushort8 loads).
__global__ __launch_bounds__(256) void k_wprep(
    const float* __restrict__ vW1, const float* __restrict__ vW2,
    const float* __restrict__ vW3,
    unsigned short* __restrict__ w1b, unsigned short* __restrict__ w2b,
    unsigned short* __restrict__ w3b,
    unsigned short* __restrict__ w2s, unsigned short* __restrict__ w3s)
{
    const int t = blockIdx.x * 256 + threadIdx.x;
    const int nth = gridDim.x * 256;
    for (int i = t; i < HVD * NN; i += nth) {          // [128 col][32 k]
        const int col = i >> 5, k = i & 31;
        w1b[i] = f2bf(vW1[k * HVD + col]);
    }
    for (int i = t; i < HVD * HVD; i += nth) {         // [128 col][128 k]
        const int col = i >> 7, k = i & 127;
        w2b[i] = f2bf(vW2[k * HVD + col]);
    }
    for (int i = t; i < 16 * HVD; i += nth) {          // [16 col][128 k], cols 8..15 = 0
        const int c = i >> 7, k = i & 127;
        w3b[i] = (c < KVD) ? f2bf(vW3[k * KVD + c]) : (unsigned short)0;
    }
    for (int i = t; i < HVD * HVD; i += nth)           // [k][col] elementwise
        w2s[i] = f2bf(vW2[i]);
    for (int i = t; i < HVD * KVD; i += nth)           // [k][c] elementwise
        w3s[i] = f2bf(vW3[i]);
}

// ---- setup: f-net fp32 (verbatim), V-net via bf16 MFMA --------------------
__global__ __launch_bounds__(256, 4) void k_setup(
    const float* __restrict__ x_g,
    const float* __restrict__ fW1, const float* __restrict__ fb1,
    const float* __restrict__ fW2, const float* __restrict__ fb2,
    const float* __restrict__ fW3, const float* __restrict__ fb3,
    const float* __restrict__ vb1, const float* __restrict__ vb2,
    const float* __restrict__ vb3,
    const unsigned short* __restrict__ w1b,
    const unsigned short* __restrict__ w2b,
    const unsigned short* __restrict__ w3b,
    const float* __restrict__ h0g,
    float* __restrict__ out,
    int* __restrict__ cnt, int* __restrict__ list, float* __restrict__ tgt,
    float* __restrict__ vfb)
{
    __shared__ float2 xs[GPB][NN + 1];                       // 4.2 KB (f-net x)
    __shared__ float fh1[GPB][HFD + 1];
    __shared__ float fh2[GPB][HFD + 1];
    __shared__ __align__(16) unsigned short abf[4][16 * 32]; // 4 KB  (Z rows bf16)
    __shared__ __align__(16) unsigned short hbf[4][16 * HVD];// 16 KB (h1/h2 reuse)
    __shared__ int wcnt[4];
    __shared__ int bbase;

    const int tid = threadIdx.x;
    const int gi = tid >> 4;          // group 0..15
    const int gl = tid & (G - 1);
    const int w  = tid >> 6;          // wave 0..3
    const int l  = tid & 63;
    const int q  = l >> 4;            // lane quad within wave (== gi & 3)
    const int cc = l & 15;
    const int sb = (blockIdx.x * GPB + gi) * 2;
    const int s0 = sb, s1 = sb + 1;
    unsigned short* aw = abf[w];
    unsigned short* hw = hbf[w];

    // ---- stage x (fp32 for f-net, bf16 rows for V A-operand) ----
    const float xa0 = x_g[(size_t)s0 * NN + gl];
    const float xa1 = x_g[(size_t)s0 * NN + gl + 16];
    const float xb0 = x_g[(size_t)s1 * NN + gl];
    const float xb1 = x_g[(size_t)s1 * NN + gl + 16];
    xs[gi][gl]      = make_float2(xa0, xb0);
    xs[gi][gl + 16] = make_float2(xa1, xb1);
    const int r0 = 4 * q;             // this group's base row in the wave tile
    aw_st(aw, r0,     gl,      xa0); aw_st(aw, r0,     gl + 16, xa1);
    aw_st(aw, r0 + 2, gl,      xb0); aw_st(aw, r0 + 2, gl + 16, xb1);
    wsync();

    // ---- f-net (fp32, feeds out[] directly -> keep precise sp_) ----
    float fA0, fA1, fB0, fB1;
#pragma unroll
    for (int si = 0; si < 2; ++si) {
        for (int uu = gl; uu < HFD; uu += G) {
            float a = fb1[uu];
#pragma unroll
            for (int i = 0; i < NN; ++i) {
                const float2 xv2 = xs[gi][i];
                const float xv = si ? xv2.y : xv2.x;
                a = fmaf(xv, fW1[i * HFD + uu], a);
            }
            fh1[gi][uu] = sp_(a);
        }
        wsync();
        for (int uu = gl; uu < HFD; uu += G) {
            float a = fb2[uu];
#pragma unroll
            for (int i = 0; i < HFD; ++i)
                a = fmaf(fh1[gi][i], fW2[i * HFD + uu], a);
            fh2[gi][uu] = sp_(a);
        }
        wsync();
        float fo0 = fb3[gl], fo1 = fb3[gl + 16];
#pragma unroll
        for (int i = 0; i < HFD; ++i) {
            const float h = fh2[gi][i];
            fo0 = fmaf(h, fW3[i * NN + gl], fo0);
            fo1 = fmaf(h, fW3[i * NN + gl + 16], fo1);
        }
        const int ss = si ? s1 : s0;
        out[(size_t)ss * NN + gl]      = fo0;
        out[(size_t)ss * NN + gl + 16] = fo1;
        aw_st(aw, r0 + 1 + 2 * si, gl,      fo0);
        aw_st(aw, r0 + 1 + 2 * si, gl + 16, fo1);
        if (si == 0) { fA0 = fo0; fA1 = fo1; } else { fB0 = fo0; fB1 = fo1; }
        wsync();
    }

    // ---- ||z||^2 per row (fp32 exact) ----
    float p0 = fmaf(xa0, xa0, xa1 * xa1);
    float p1 = fmaf(fA0, fA0, fA1 * fA1);
    float p2 = fmaf(xb0, xb0, xb1 * xb1);
    float p3 = fmaf(fB0, fB0, fB1 * fB1);
#pragma unroll
    for (int m = 1; m < G; m <<= 1) {
        p0 += __shfl_xor(p0, m); p1 += __shfl_xor(p1, m);
        p2 += __shfl_xor(p2, m); p3 += __shfl_xor(p3, m);
    }

    float b1v[8], b2v[8];
#pragma unroll
    for (int n = 0; n < 8; ++n) {
        b1v[n] = vb1[n * 16 + cc];    // col = n*16 + cc
        b2v[n] = vb2[n * 16 + cc];
    }

    const int kq = (l >> 4) * 8;      // this lane's k-offset within a K=32 chunk
    const f32x4 zf = {0.f, 0.f, 0.f, 0.f};

    // ---- V layer 1: u[16][128] = Z[16][32] @ W1  (8 MFMA, K=32 exact) ----
    const bf16x8 afr = aw_ld(aw, cc, kq);        // A: row=l&15, k=8*(l>>4)+j
    f32x4 acc1[8];
#pragma unroll
    for (int n = 0; n < 8; ++n) {
        const bf16x8 bfr = *(const bf16x8*)(w1b + (n * 16 + cc) * 32 + kq);
        acc1[n] = __builtin_amdgcn_mfma_f32_16x16x32_bf16(afr, bfr, zf, 0, 0, 0);
    }
    // h1 = softplus(u + b1) -> hbf (C layout: row=4q+r, col=n*16+cc)
#pragma unroll
    for (int n = 0; n < 8; ++n) {
#pragma unroll
        for (int r = 0; r < 4; ++r)
            hw_st(hw, r0 + r, n * 16 + cc, spf_(acc1[n][r] + b1v[n]));
    }
    wsync();

    // ---- V layer 2: a2[16][128] = H1 @ W2  (32 MFMA) ----
    f32x4 acc2[8];
#pragma unroll
    for (int n = 0; n < 8; ++n) acc2[n] = zf;
#pragma unroll
    for (int c = 0; c < 4; ++c) {
        const bf16x8 a2f = hw_ld(hw, cc, c * 32 + kq);
#pragma unroll
        for (int n = 0; n < 8; ++n) {
            const bf16x8 b2f = *(const bf16x8*)(w2b + (n * 16 + cc) * HVD + c * 32 + kq);
            acc2[n] = __builtin_amdgcn_mfma_f32_16x16x32_bf16(a2f, b2f, acc2[n], 0, 0, 0);
        }
    }
    wsync();   // all W2 A-reads done before overwriting hbf with h2
#pragma unroll
    for (int n = 0; n < 8; ++n) {
#pragma unroll
        for (int r = 0; r < 4; ++r)
            hw_st(hw, r0 + r, n * 16 + cc, spf_(acc2[n][r] + b2v[n]));
    }
    wsync();

    // ---- V layer 3: o[16][16] = H2 @ W3pad  (4 MFMA, cols 8..15 zero) ----
    f32x4 acc3 = zf;
#pragma unroll
    for (int c = 0; c < 4; ++c) {
        const bf16x8 a3f = hw_ld(hw, cc, c * 32 + kq);
        const bf16x8 b3f = *(const bf16x8*)(w3b + cc * HVD + c * 32 + kq);
        acc3 = __builtin_amdgcn_mfma_f32_16x16x32_bf16(a3f, b3f, acc3, 0, 0, 0);
    }

    // ---- finalize V per row; rows 4q+r belong to THIS group's samples ----
    const float d0 = (cc < KVD) ? (vb3[cc] - h0g[cc]) : 0.f;
    float s_[4];
#pragma unroll
    for (int r = 0; r < 4; ++r) {
        const float e = (cc < KVD) ? (acc3[r] + d0) : 0.f;  // zero pad lanes
        s_[r] = e * e;
    }
#pragma unroll
    for (int m = 1; m < G; m <<= 1) {
#pragma unroll
        for (int r = 0; r < 4; ++r) s_[r] += __shfl_xor(s_[r], m);
    }
    const float Vx0 = s_[0] + EPS_C * p0;
    const float Vf0 = s_[1] + EPS_C * p1;
    const float Vx1 = s_[2] + EPS_C * p2;
    const float Vf1 = s_[3] + EPS_C * p3;

    const float t0 = BETA_C * Vx0;
    const float t1 = BETA_C * Vx1;
    const bool act0 = (Vf0 - t0) > 0.f;        // group-uniform
    const bool act1 = (Vf1 - t1) > 0.f;

    const bool lead = (gl == 0 && act0) || (gl == 1 && act1);
    unsigned long long bal = __ballot(lead);
    const int lane = threadIdx.x & 63, wv = threadIdx.x >> 6;
    const int rank = __popcll(bal & ((1ull << lane) - 1ull));
    if (lane == 0) wcnt[wv] = __popcll(bal);
    __syncthreads();
    if (threadIdx.x == 0) {
        int tot = 0;
        for (int i = 0; i < 4; ++i) { int c = wcnt[i]; wcnt[i] = tot; tot += c; }
        bbase = atomicAdd(cnt, tot);
    }
    __syncthreads();
    if (lead) {
        const int p = bbase + wcnt[wv] + rank;
        list[p] = (gl == 0) ? s0 : s1;
        tgt[p]  = (gl == 0) ? t0 : t1;
        vfb[p]  = (gl == 0) ? Vf0 : Vf1;       // V(fhatx) — solver's V(1)
    }
}

// ---- solver: persistent groups, PAIRED samples, SAFEGUARDED Newton --------
// Bracket updated on EVERY eval; FORCE_C caps Newton; BRK_C accepts when the
// bracket collapses.  W2/W3 read as bf16 (see veval2_tan).
__global__ __launch_bounds__(64, 2) void k_solve(
    const float* __restrict__ vW1, const float* __restrict__ vb1,
    const unsigned short* __restrict__ w2s, const float* __restrict__ vb2,
    const unsigned short* __restrict__ w3s, const float* __restrict__ vb3,
    const float* __restrict__ h0g,
    float* __restrict__ out,
    const int* __restrict__ cnt, const int* __restrict__ list,
    const float* __restrict__ tgt, const float* __restrict__ vfb,
    int* __restrict__ qhead)
{
    __shared__ __align__(16) float4 h1s[SGPB][HVD + 2];
    __shared__ __align__(16) float2 fxs[SGPB][NN + 2];

    const int gi = threadIdx.x >> 4;
    const int gl = threadIdx.x & (G - 1);
    const int n  = *cnt;
    float4* h1q = h1s[gi];
    float2* fxr = fxs[gi];
    const int lead = threadIdx.x & 48;

    const int k0 = gl * 8;
    float b1v[8], b2v[8], d0c[8];
    {
        const float4 a = *(const float4*)(vb1 + k0);
        const float4 b = *(const float4*)(vb1 + k0 + 4);
        b1v[0]=a.x; b1v[1]=a.y; b1v[2]=a.z; b1v[3]=a.w;
        b1v[4]=b.x; b1v[5]=b.y; b1v[6]=b.z; b1v[7]=b.w;
        const float4 c = *(const float4*)(vb2 + k0);
        const float4 d = *(const float4*)(vb2 + k0 + 4);
        b2v[0]=c.x; b2v[1]=c.y; b2v[2]=c.z; b2v[3]=c.w;
        b2v[4]=d.x; b2v[5]=d.y; b2v[6]=d.z; b2v[7]=d.w;
#pragma unroll
        for (int cix = 0; cix < KVD; ++cix) d0c[cix] = vb3[cix] - h0g[cix];
    }

    int sA, sB; float tgA, tgB, fA0, fA1, fB0, fB1, n2A, n2B;
    float uA[8], uB[8];
    float gA, e1A, e2A, vA1, vA2;
    float gB, e1B, e2B, vB1, vB2;
    bool doneA, doneB;
    int itA, itB;

    auto grab = [&]() -> bool {
        int v = 0;
        if (gl == 0) v = atomicAdd(qhead, 2);
        v = __shfl(v, lead);
        if (v >= n) return false;
        const bool hasB = (v + 1) < n;
        sA = list[v]; tgA = tgt[v];
        const float vfA = vfb[v];
        float vfB;
        if (hasB) { sB = list[v + 1]; tgB = tgt[v + 1]; vfB = vfb[v + 1]; }
        else      { sB = sA;          tgB = tgA;        vfB = vfA; }
        fA0 = out[(size_t)sA * NN + gl];
        fA1 = out[(size_t)sA * NN + gl + 16];
        fB0 = out[(size_t)sB * NN + gl];
        fB1 = out[(size_t)sB * NN + gl + 16];
        fxr[gl]      = make_float2(fA0, fB0);
        fxr[gl + 16] = make_float2(fA1, fB1);
        wsync();
        n2A = 0.f; n2B = 0.f;
#pragma unroll
        for (int i = 0; i < NN; ++i) {
            const float2 q = fxr[i];
            n2A = fmaf(q.x, q.x, n2A);
            n2B = fmaf(q.y, q.y, n2B);
        }
#pragma unroll
        for (int j = 0; j < 8; ++j) { uA[j] = 0.f; uB[j] = 0.f; }
#pragma unroll
        for (int i = 0; i < NN; ++i) {
            const float2 q = fxr[i];
            const float4 wa = *(const float4*)(vW1 + i * HVD + k0);
            const float4 wb = *(const float4*)(vW1 + i * HVD + k0 + 4);
            uA[0] = fmaf(q.x, wa.x, uA[0]); uA[1] = fmaf(q.x, wa.y, uA[1]);
            uA[2] = fmaf(q.x, wa.z, uA[2]); uA[3] = fmaf(q.x, wa.w, uA[3]);
            uA[4] = fmaf(q.x, wb.x, uA[4]); uA[5] = fmaf(q.x, wb.y, uA[5]);
            uA[6] = fmaf(q.x, wb.z, uA[6]); uA[7] = fmaf(q.x, wb.w, uA[7]);
            uB[0] = fmaf(q.y, wa.x, uB[0]); uB[1] = fmaf(q.y, wa.y, uB[1]);
            uB[2] = fmaf(q.y, wa.z, uB[2]); uB[3] = fmaf(q.y, wa.w, uB[3]);
            uB[4] = fmaf(q.y, wb.x, uB[4]); uB[5] = fmaf(q.y, wb.y, uB[5]);
            uB[6] = fmaf(q.y, wb.z, uB[6]); uB[7] = fmaf(q.y, wb.w, uB[7]);
        }
        gA = sqrtf(tgA / vfA); e1A = 0.f; e2A = 1.f; vA1 = 0.f; vA2 = vfA;
        gB = sqrtf(tgB / vfB); e1B = 0.f; e2B = 1.f; vB1 = 0.f; vB2 = vfB;
        doneA = false; itA = 0;
        doneB = !hasB; itB = 0;
        return true;
    };
    if (!grab()) return;

    auto step = [&](bool& done, float& gamma, float& e1, float& e2,
                    float& v_e1, float& v_e2, int& it,
                    const float vp, const float dv, const float target,
                    const int s, const float f0, const float f1) {
        if (done) return;
        // accept: at tolerance, bracket collapsed, or iteration cap
        if (fabsf(vp - target) <= TOL_C || (e2 - e1) <= BRK_C) {
            out[(size_t)s * NN + gl]      = f0 * gamma;
            out[(size_t)s * NN + gl + 16] = f1 * gamma;
            done = true;
            return;
        }
        // ALWAYS contract the bracket with this eval.
        const float sa = sgn_(vp - target);
        const float s1 = sgn_(v_e1 - target);
        if (sa * s1 < 0.f) { e2 = gamma; v_e2 = vp; }
        else               { e1 = gamma; v_e1 = vp; }
        ++it;
        const float newt = gamma - (vp - target) / dv;
        if (it < FORCE_C && newt >= e1 && newt <= e2) {   // NaN fails -> bisect
            if (fabsf(newt - gamma) <= ACC_C) {
                // early accept: skip verification eval
                out[(size_t)s * NN + gl]      = f0 * newt;
                out[(size_t)s * NN + gl + 16] = f1 * newt;
                done = true;
                return;
            }
            gamma = newt;
        } else {
            gamma = 0.5f * (e1 + e2);                     // guaranteed shrink
        }
        if (it >= MAXIT_C) {
            out[(size_t)s * NN + gl]      = f0 * gamma;
            out[(size_t)s * NN + gl + 16] = f1 * gamma;
            done = true;
        }
    };

    for (;;) {
        float vpA, dvA, vpB, dvB;
        veval2_tan(gl, uA, uB, gA, gB, h1q, n2A, n2B,
                   b1v, b2v, d0c, w2s, w3s, vpA, dvA, vpB, dvB);
        step(doneA, gA, e1A, e2A, vA1, vA2, itA, vpA, dvA, tgA, sA, fA0, fA1);
        step(doneB, gB, e1B, e2B, vB1, vB2, itB, vpB, dvB, tgB, sB, fB0, fB1);
        if (doneA && doneB) {
            if (!grab()) break;
        }
    }
}

extern "C" void kernel_launch(void* const* d_in, const int* in_sizes, int n_in,
                              void* d_out, int out_size, void* d_ws, size_t ws_size,
                              hipStream_t stream)
{
    const float* x   = (const float*)d_in[0];
    const float* fW1 = (const float*)d_in[1];
    const float* fb1 = (const float*)d_in[2];
    const float* fW2 = (const float*)d_in[3];
    const float* fb2 = (const float*)d_in[4];
    const float* fW3 = (const float*)d_in[5];
    const float* fb3 = (const float*)d_in[6];
    const float* vW1 = (const float*)d_in[7];
    const float* vb1 = (const float*)d_in[8];
    const float* vW2 = (const float*)d_in[9];
    const float* vb2 = (const float*)d_in[10];
    const float* vW3 = (const float*)d_in[11];
    const float* vb3 = (const float*)d_in[12];
    float* out = (float*)d_out;

    char* ws = (char*)d_ws;
    int*   cnt   = (int*)ws;                                 // 4 B
    int*   qhead = (int*)(ws + 4);                           // 4 B
    float* h0g   = (float*)(ws + 64);                        // 8 floats
    int*   list  = (int*)(ws + 128);                         // BN ints
    float* tgt   = (float*)(ws + 128 + (size_t)BN * 4);      // BN floats
    float* vfb   = (float*)(ws + 128 + (size_t)BN * 8);      // BN floats
    unsigned short* w1b = (unsigned short*)(ws + 128 + (size_t)BN * 12);  // 8 KB (16B-aligned)
    unsigned short* w2b = w1b + HVD * NN;                    // 32 KB
    unsigned short* w3b = w2b + HVD * HVD;                   // 4 KB
    unsigned short* w2s = w3b + 16 * HVD;                    // 32 KB (solver, [k][col])
    unsigned short* w3s = w2s + HVD * HVD;                   // 2 KB  (solver, [k][c])

    hipMemsetAsync(ws, 0, 8, stream);                        // cnt + qhead

    hipLaunchKernelGGL(k_h0, dim3(1), dim3(HVD), 0, stream,
                       vb1, vW2, vb2, vW3, vb3, h0g);

    hipLaunchKernelGGL(k_wprep, dim3(32), dim3(256), 0, stream,
                       vW1, vW2, vW3, w1b, w2b, w3b, w2s, w3s);

    hipLaunchKernelGGL(k_setup, dim3(BN / (GPB * 2)), dim3(256), 0, stream,
                       x, fW1, fb1, fW2, fb2, fW3, fb3,
                       vb1, vb2, vb3, w1b, w2b, w3b,
                       h0g, out, cnt, list, tgt, vfb);

    hipLaunchKernelGGL(k_solve, dim3(NQBLK), dim3(64), 0, stream,
                       vW1, vb1, w2s, vb2, w3s, vb3,
                       h0g, out, cnt, list, tgt, vfb, qhead);
}

// Round 4
// 418.961 us; speedup vs baseline: 2.3979x; 1.2751x over previous
//
#include <hip/hip_runtime.h>
#include <math.h>

#define BETA_C   0.99f
#define TOL_C    1e-4f
#define ACC_C    1e-3f   // early-accept: Newton step smaller than this -> done
#define BRK_C    2e-4f   // bracket-width accept (gamma err 2e-4 -> out err ~1e-3*|fx|)
#define FORCE_C  6       // Newton gets 6 tries, then pure bisection
#define MAXIT_C  1000
#define EPS_C    1e-3f
#define BN       65536
#define NN       32
#define HFD      25
#define HVD      128
#define KVD      8
#define G        16   // lanes per cooperative group
#define GPB      16   // groups per 256-thread block (k_setup; 2 samples/group)
#define SGPB     4    // groups per 64-thread block (k_solve)
#define NQBLK    4096 // persistent solver blocks (16 waves/CU; queue-drained)

typedef __attribute__((ext_vector_type(8))) short bf16x8;  // 8 bf16 (4 VGPRs)
typedef __attribute__((ext_vector_type(8))) unsigned short u16x8;
typedef __attribute__((ext_vector_type(4))) float f32x4;   // 4 fp32 acc

// wave-internal LDS ordering (groups live inside one wave; no block barrier
// inside the divergent solve loop).
__device__ __forceinline__ void wsync() {
    __builtin_amdgcn_wave_barrier();
    __threadfence_block();
    __builtin_amdgcn_wave_barrier();
}

__device__ __forceinline__ float sp_(float x) {
    return fmaxf(x, 0.f) + log1pf(expf(-fabsf(x)));
}
// fast softplus for the bf16 MFMA V-path (feeds bf16 rounding anyway)
__device__ __forceinline__ float spf_(float x) {
    return fmaxf(x, 0.f) + __logf(1.f + __expf(-fabsf(x)));
}
__device__ __forceinline__ void spsig_(float x, float& sp, float& sg) {
    float t = expf(-fabsf(x));
    sp = fmaxf(x, 0.f) + log1pf(t);
    float r = 1.f / (1.f + t);
    sg = (x >= 0.f) ? r : t * r;
}
__device__ __forceinline__ float sgn_(float d) {
    return (d > 0.f) ? 1.f : ((d < 0.f) ? -1.f : 0.f);
}
__device__ __forceinline__ unsigned short f2bf(float f) {   // RNE f32->bf16
    unsigned int u = __float_as_uint(f);
    u += 0x7FFFu + ((u >> 16) & 1u);
    return (unsigned short)(u >> 16);
}
__device__ __forceinline__ float bf2f(unsigned short u) {
    return __uint_as_float(((unsigned int)u) << 16);
}

// ---- swizzled per-wave LDS activation tiles (G4: XOR row bits into bank bits)
__device__ __forceinline__ void aw_st(unsigned short* aw, int row, int col, float v) {
    const int b = (row * 64 + col * 2) ^ ((row & 3) << 4);
    *(unsigned short*)((char*)aw + b) = f2bf(v);
}
__device__ __forceinline__ bf16x8 aw_ld(const unsigned short* aw, int row, int k) {
    const int b = (row * 64 + k * 2) ^ ((row & 3) << 4);
    return *(const bf16x8*)((const char*)aw + b);
}
__device__ __forceinline__ void hw_st(unsigned short* hw, int row, int col, float v) {
    const int b = (row * 256 + col * 2) ^ ((row & 7) << 4);
    *(unsigned short*)((char*)hw + b) = f2bf(v);
}
__device__ __forceinline__ bf16x8 hw_ld(const unsigned short* hw, int row, int k) {
    const int b = (row * 256 + k * 2) ^ ((row & 7) << 4);
    return *(const bf16x8*)((const char*)hw + b);
}

// ---------------------------------------------------------------------------
// paired TAN eval (k_solve): V(fxA*gA), V(fxB*gB) + derivatives, sharing all
// W2/W3 loads.  W2/W3 read as bf16 (w2s[k][col], w3s[k][c]) -> one ushort8
// load/iter; 32KB W2 fits L1.  Activations fp32 -> V(gamma) smooth.
__device__ __forceinline__ void veval2_tan(
    const int gl, const float (&uA)[8], const float (&uB)[8],
    const float gA, const float gB,
    float4* h1q, const float n2A, const float n2B,
    const float (&b1v)[8], const float (&b2v)[8], const float (&d0c)[8],
    const unsigned short* __restrict__ w2s, const unsigned short* __restrict__ w3s,
    float& VA, float& dVA, float& VB, float& dVB)
{
    const int k0 = gl * 8;
#pragma unroll
    for (int j = 0; j < 8; ++j) {
        const float preA = fmaf(gA, uA[j], b1v[j]);
        const float preB = fmaf(gB, uB[j], b1v[j]);
        float spA, sgA, spB, sgB;
        spsig_(preA, spA, sgA);
        spsig_(preB, spB, sgB);
        h1q[k0 + j] = make_float4(spA, sgA * uA[j], spB, sgB * uB[j]);
    }
    wsync();
    float aA[8], dA[8], aB[8], dB[8];
#pragma unroll
    for (int j = 0; j < 8; ++j) { aA[j] = 0.f; dA[j] = 0.f; aB[j] = 0.f; dB[j] = 0.f; }
#pragma unroll 2
    for (int k = 0; k < HVD; ++k) {
        const float4 q = h1q[k];                       // broadcast
        const u16x8 wv = *(const u16x8*)(w2s + k * HVD + k0);
        float w[8];
#pragma unroll
        for (int j = 0; j < 8; ++j) w[j] = bf2f(wv[j]);
#pragma unroll
        for (int j = 0; j < 8; ++j) {
            aA[j] = fmaf(q.x, w[j], aA[j]);
            dA[j] = fmaf(q.y, w[j], dA[j]);
            aB[j] = fmaf(q.z, w[j], aB[j]);
            dB[j] = fmaf(q.w, w[j], dB[j]);
        }
    }
    wsync();
    float oA[KVD], pA[KVD], oB[KVD], pB[KVD];
#pragma unroll
    for (int c = 0; c < KVD; ++c) { oA[c] = 0.f; pA[c] = 0.f; oB[c] = 0.f; pB[c] = 0.f; }
#pragma unroll
    for (int j = 0; j < 8; ++j) {
        float h2A, sA; spsig_(aA[j] + b2v[j], h2A, sA);
        const float dh2A = sA * dA[j];
        float h2B, sB; spsig_(aB[j] + b2v[j], h2B, sB);
        const float dh2B = sB * dB[j];
        const u16x8 w3v = *(const u16x8*)(w3s + (k0 + j) * KVD);
        float w3[8];
#pragma unroll
        for (int c = 0; c < 8; ++c) w3[c] = bf2f(w3v[c]);
#pragma unroll
        for (int c = 0; c < 8; ++c) {
            oA[c] = fmaf(h2A,  w3[c], oA[c]);
            pA[c] = fmaf(dh2A, w3[c], pA[c]);
            oB[c] = fmaf(h2B,  w3[c], oB[c]);
            pB[c] = fmaf(dh2B, w3[c], pB[c]);
        }
    }
#pragma unroll
    for (int m = 1; m < G; m <<= 1) {
#pragma unroll
        for (int c = 0; c < KVD; ++c) {
            oA[c] += __shfl_xor(oA[c], m);
            pA[c] += __shfl_xor(pA[c], m);
            oB[c] += __shfl_xor(oB[c], m);
            pB[c] += __shfl_xor(pB[c], m);
        }
    }
    float vvA = 0.f, dvA = 0.f, vvB = 0.f, dvB = 0.f;
#pragma unroll
    for (int c = 0; c < KVD; ++c) {
        const float eA = oA[c] + d0c[c];
        const float eB = oB[c] + d0c[c];
        vvA = fmaf(eA, eA, vvA);
        dvA = fmaf(eA, pA[c], dvA);
        vvB = fmaf(eB, eB, vvB);
        dvB = fmaf(eB, pB[c], dvB);
    }
    VA  = vvA + EPS_C * gA * gA * n2A;
    dVA = 2.f * dvA + 2.f * EPS_C * gA * n2A;
    VB  = vvB + EPS_C * gB * gB * n2B;
    dVB = 2.f * dvB + 2.f * EPS_C * gB * n2B;
}

// ---- h0 = V-MLP(0) : weight-only, one tiny block --------------------------
__global__ __launch_bounds__(128) void k_h0(
    const float* __restrict__ vb1, const float* __restrict__ vW2,
    const float* __restrict__ vb2, const float* __restrict__ vW3,
    const float* __restrict__ vb3, float* __restrict__ h0g)
{
    __shared__ float h1s[HVD];
    __shared__ float h2s[HVD];
    int j = threadIdx.x;
    h1s[j] = sp_(vb1[j]);
    __syncthreads();
    float a = vb2[j];
    for (int k = 0; k < HVD; ++k) a = fmaf(h1s[k], vW2[k * HVD + j], a);
    h2s[j] = sp_(a);
    __syncthreads();
    if (j < KVD) {
        float acc = vb3[j];
        for (int k = 0; k < HVD; ++k) acc = fmaf(h2s[k], vW3[k * KVD + j], acc);
        h0g[j] = acc;
    }
}

// ---- weight prep: V-net weights -> bf16 ------------------------------------
__global__ __launch_bounds__(256) void k_wprep(
    const float* __restrict__ vW1, const float* __restrict__ vW2,
    const float* __restrict__ vW3,
    unsigned short* __restrict__ w1b, unsigned short* __restrict__ w2b,
    unsigned short* __restrict__ w3b,
    unsigned short* __restrict__ w2s, unsigned short* __restrict__ w3s)
{
    const int t = blockIdx.x * 256 + threadIdx.x;
    const int nth = gridDim.x * 256;
    for (int i = t; i < HVD * NN; i += nth) {          // [128 col][32 k]
        const int col = i >> 5, k = i & 31;
        w1b[i] = f2bf(vW1[k * HVD + col]);
    }
    for (int i = t; i < HVD * HVD; i += nth) {         // [128 col][128 k]
        const int col = i >> 7, k = i & 127;
        w2b[i] = f2bf(vW2[k * HVD + col]);
    }
    for (int i = t; i < 16 * HVD; i += nth) {          // [16 col][128 k], cols 8..15 = 0
        const int c = i >> 7, k = i & 127;
        w3b[i] = (c < KVD) ? f2bf(vW3[k * KVD + c]) : (unsigned short)0;
    }
    for (int i = t; i < HVD * HVD; i += nth)           // [k][col] elementwise
        w2s[i] = f2bf(vW2[i]);
    for (int i = t; i < HVD * KVD; i += nth)           // [k][c] elementwise
        w3s[i] = f2bf(vW3[i]);
}

// ---- setup: f-net fp32 (verbatim), V-net via bf16 MFMA --------------------
__global__ __launch_bounds__(256, 4) void k_setup(
    const float* __restrict__ x_g,
    const float* __restrict__ fW1, const float* __restrict__ fb1,
    const float* __restrict__ fW2, const float* __restrict__ fb2,
    const float* __restrict__ fW3, const float* __restrict__ fb3,
    const float* __restrict__ vb1, const float* __restrict__ vb2,
    const float* __restrict__ vb3,
    const unsigned short* __restrict__ w1b,
    const unsigned short* __restrict__ w2b,
    const unsigned short* __restrict__ w3b,
    const float* __restrict__ h0g,
    float* __restrict__ out,
    int* __restrict__ cnt, int* __restrict__ list, float* __restrict__ tgt,
    float* __restrict__ vfb)
{
    __shared__ float2 xs[GPB][NN + 1];                       // 4.2 KB (f-net x)
    __shared__ float fh1[GPB][HFD + 1];
    __shared__ float fh2[GPB][HFD + 1];
    __shared__ __align__(16) unsigned short abf[4][16 * 32]; // 4 KB  (Z rows bf16)
    __shared__ __align__(16) unsigned short hbf[4][16 * HVD];// 16 KB (h1/h2 reuse)
    __shared__ int wcnt[4];
    __shared__ int bbase;

    const int tid = threadIdx.x;
    const int gi = tid >> 4;          // group 0..15
    const int gl = tid & (G - 1);
    const int w  = tid >> 6;          // wave 0..3
    const int l  = tid & 63;
    const int q  = l >> 4;            // lane quad within wave (== gi & 3)
    const int cc = l & 15;
    const int sb = (blockIdx.x * GPB + gi) * 2;
    const int s0 = sb, s1 = sb + 1;
    unsigned short* aw = abf[w];
    unsigned short* hw = hbf[w];

    // ---- stage x (fp32 for f-net, bf16 rows for V A-operand) ----
    const float xa0 = x_g[(size_t)s0 * NN + gl];
    const float xa1 = x_g[(size_t)s0 * NN + gl + 16];
    const float xb0 = x_g[(size_t)s1 * NN + gl];
    const float xb1 = x_g[(size_t)s1 * NN + gl + 16];
    xs[gi][gl]      = make_float2(xa0, xb0);
    xs[gi][gl + 16] = make_float2(xa1, xb1);
    const int r0 = 4 * q;             // this group's base row in the wave tile
    aw_st(aw, r0,     gl,      xa0); aw_st(aw, r0,     gl + 16, xa1);
    aw_st(aw, r0 + 2, gl,      xb0); aw_st(aw, r0 + 2, gl + 16, xb1);
    wsync();

    // ---- f-net (fp32, feeds out[] directly -> keep precise sp_) ----
    float fA0, fA1, fB0, fB1;
#pragma unroll
    for (int si = 0; si < 2; ++si) {
        for (int uu = gl; uu < HFD; uu += G) {
            float a = fb1[uu];
#pragma unroll
            for (int i = 0; i < NN; ++i) {
                const float2 xv2 = xs[gi][i];
                const float xv = si ? xv2.y : xv2.x;
                a = fmaf(xv, fW1[i * HFD + uu], a);
            }
            fh1[gi][uu] = sp_(a);
        }
        wsync();
        for (int uu = gl; uu < HFD; uu += G) {
            float a = fb2[uu];
#pragma unroll
            for (int i = 0; i < HFD; ++i)
                a = fmaf(fh1[gi][i], fW2[i * HFD + uu], a);
            fh2[gi][uu] = sp_(a);
        }
        wsync();
        float fo0 = fb3[gl], fo1 = fb3[gl + 16];
#pragma unroll
        for (int i = 0; i < HFD; ++i) {
            const float h = fh2[gi][i];
            fo0 = fmaf(h, fW3[i * NN + gl], fo0);
            fo1 = fmaf(h, fW3[i * NN + gl + 16], fo1);
        }
        const int ss = si ? s1 : s0;
        out[(size_t)ss * NN + gl]      = fo0;
        out[(size_t)ss * NN + gl + 16] = fo1;
        aw_st(aw, r0 + 1 + 2 * si, gl,      fo0);
        aw_st(aw, r0 + 1 + 2 * si, gl + 16, fo1);
        if (si == 0) { fA0 = fo0; fA1 = fo1; } else { fB0 = fo0; fB1 = fo1; }
        wsync();
    }

    // ---- ||z||^2 per row (fp32 exact) ----
    float p0 = fmaf(xa0, xa0, xa1 * xa1);
    float p1 = fmaf(fA0, fA0, fA1 * fA1);
    float p2 = fmaf(xb0, xb0, xb1 * xb1);
    float p3 = fmaf(fB0, fB0, fB1 * fB1);
#pragma unroll
    for (int m = 1; m < G; m <<= 1) {
        p0 += __shfl_xor(p0, m); p1 += __shfl_xor(p1, m);
        p2 += __shfl_xor(p2, m); p3 += __shfl_xor(p3, m);
    }

    float b1v[8], b2v[8];
#pragma unroll
    for (int n = 0; n < 8; ++n) {
        b1v[n] = vb1[n * 16 + cc];    // col = n*16 + cc
        b2v[n] = vb2[n * 16 + cc];
    }

    const int kq = (l >> 4) * 8;      // this lane's k-offset within a K=32 chunk
    const f32x4 zf = {0.f, 0.f, 0.f, 0.f};

    // ---- V layer 1: u[16][128] = Z[16][32] @ W1  (8 MFMA, K=32 exact) ----
    const bf16x8 afr = aw_ld(aw, cc, kq);        // A: row=l&15, k=8*(l>>4)+j
    f32x4 acc1[8];
#pragma unroll
    for (int n = 0; n < 8; ++n) {
        const bf16x8 bfr = *(const bf16x8*)(w1b + (n * 16 + cc) * 32 + kq);
        acc1[n] = __builtin_amdgcn_mfma_f32_16x16x32_bf16(afr, bfr, zf, 0, 0, 0);
    }
    // h1 = softplus(u + b1) -> hbf (C layout: row=4q+r, col=n*16+cc)
#pragma unroll
    for (int n = 0; n < 8; ++n) {
#pragma unroll
        for (int r = 0; r < 4; ++r)
            hw_st(hw, r0 + r, n * 16 + cc, spf_(acc1[n][r] + b1v[n]));
    }
    wsync();

    // ---- V layer 2: a2[16][128] = H1 @ W2  (32 MFMA) ----
    f32x4 acc2[8];
#pragma unroll
    for (int n = 0; n < 8; ++n) acc2[n] = zf;
#pragma unroll
    for (int c = 0; c < 4; ++c) {
        const bf16x8 a2f = hw_ld(hw, cc, c * 32 + kq);
#pragma unroll
        for (int n = 0; n < 8; ++n) {
            const bf16x8 b2f = *(const bf16x8*)(w2b + (n * 16 + cc) * HVD + c * 32 + kq);
            acc2[n] = __builtin_amdgcn_mfma_f32_16x16x32_bf16(a2f, b2f, acc2[n], 0, 0, 0);
        }
    }
    wsync();   // all W2 A-reads done before overwriting hbf with h2
#pragma unroll
    for (int n = 0; n < 8; ++n) {
#pragma unroll
        for (int r = 0; r < 4; ++r)
            hw_st(hw, r0 + r, n * 16 + cc, spf_(acc2[n][r] + b2v[n]));
    }
    wsync();

    // ---- V layer 3: o[16][16] = H2 @ W3pad  (4 MFMA, cols 8..15 zero) ----
    f32x4 acc3 = zf;
#pragma unroll
    for (int c = 0; c < 4; ++c) {
        const bf16x8 a3f = hw_ld(hw, cc, c * 32 + kq);
        const bf16x8 b3f = *(const bf16x8*)(w3b + cc * HVD + c * 32 + kq);
        acc3 = __builtin_amdgcn_mfma_f32_16x16x32_bf16(a3f, b3f, acc3, 0, 0, 0);
    }

    // ---- finalize V per row; rows 4q+r belong to THIS group's samples ----
    const float d0 = (cc < KVD) ? (vb3[cc] - h0g[cc]) : 0.f;
    float s_[4];
#pragma unroll
    for (int r = 0; r < 4; ++r) {
        const float e = (cc < KVD) ? (acc3[r] + d0) : 0.f;  // zero pad lanes
        s_[r] = e * e;
    }
#pragma unroll
    for (int m = 1; m < G; m <<= 1) {
#pragma unroll
        for (int r = 0; r < 4; ++r) s_[r] += __shfl_xor(s_[r], m);
    }
    const float Vx0 = s_[0] + EPS_C * p0;
    const float Vf0 = s_[1] + EPS_C * p1;
    const float Vx1 = s_[2] + EPS_C * p2;
    const float Vf1 = s_[3] + EPS_C * p3;

    const float t0 = BETA_C * Vx0;
    const float t1 = BETA_C * Vx1;
    const bool act0 = (Vf0 - t0) > 0.f;        // group-uniform
    const bool act1 = (Vf1 - t1) > 0.f;

    const bool lead = (gl == 0 && act0) || (gl == 1 && act1);
    unsigned long long bal = __ballot(lead);
    const int lane = threadIdx.x & 63, wv = threadIdx.x >> 6;
    const int rank = __popcll(bal & ((1ull << lane) - 1ull));
    if (lane == 0) wcnt[wv] = __popcll(bal);
    __syncthreads();
    if (threadIdx.x == 0) {
        int tot = 0;
        for (int i = 0; i < 4; ++i) { int c = wcnt[i]; wcnt[i] = tot; tot += c; }
        bbase = atomicAdd(cnt, tot);
    }
    __syncthreads();
    if (lead) {
        const int p = bbase + wcnt[wv] + rank;
        list[p] = (gl == 0) ? s0 : s1;
        tgt[p]  = (gl == 0) ? t0 : t1;
        vfb[p]  = (gl == 0) ? Vf0 : Vf1;       // V(fhatx) — solver's V(1)
    }
}

// ---- solver: persistent groups, PAIRED samples, SAFEGUARDED Newton --------
// R4: boundary-accept.  The bf16-tgt vs fp32-V "no-root" band (V(g)<tgt for
// all g in [0,1]) has the signature: Newton proposes newt>e2 while e2 is
// still the never-contracted initial 1.0 (a genuine interior root would have
// produced a V>tgt eval and contracted e2).  Reference classifies these
// samples as NON-violating (fp32-consistent V) -> reference output is
// fhatx*1.  So on the 2nd such event we accept gamma=1 exactly -> matches
// reference, and collapses the ~18-eval serial grind (R3's ~200us
// low-occupancy tail) to ~3 evals.
__global__ __launch_bounds__(64, 2) void k_solve(
    const float* __restrict__ vW1, const float* __restrict__ vb1,
    const unsigned short* __restrict__ w2s, const float* __restrict__ vb2,
    const unsigned short* __restrict__ w3s, const float* __restrict__ vb3,
    const float* __restrict__ h0g,
    float* __restrict__ out,
    const int* __restrict__ cnt, const int* __restrict__ list,
    const float* __restrict__ tgt, const float* __restrict__ vfb,
    int* __restrict__ qhead)
{
    __shared__ __align__(16) float4 h1s[SGPB][HVD + 2];
    __shared__ __align__(16) float2 fxs[SGPB][NN + 2];

    const int gi = threadIdx.x >> 4;
    const int gl = threadIdx.x & (G - 1);
    const int n  = *cnt;
    float4* h1q = h1s[gi];
    float2* fxr = fxs[gi];
    const int lead = threadIdx.x & 48;

    const int k0 = gl * 8;
    float b1v[8], b2v[8], d0c[8];
    {
        const float4 a = *(const float4*)(vb1 + k0);
        const float4 b = *(const float4*)(vb1 + k0 + 4);
        b1v[0]=a.x; b1v[1]=a.y; b1v[2]=a.z; b1v[3]=a.w;
        b1v[4]=b.x; b1v[5]=b.y; b1v[6]=b.z; b1v[7]=b.w;
        const float4 c = *(const float4*)(vb2 + k0);
        const float4 d = *(const float4*)(vb2 + k0 + 4);
        b2v[0]=c.x; b2v[1]=c.y; b2v[2]=c.z; b2v[3]=c.w;
        b2v[4]=d.x; b2v[5]=d.y; b2v[6]=d.z; b2v[7]=d.w;
#pragma unroll
        for (int cix = 0; cix < KVD; ++cix) d0c[cix] = vb3[cix] - h0g[cix];
    }

    int sA, sB; float tgA, tgB, fA0, fA1, fB0, fB1, n2A, n2B;
    float uA[8], uB[8];
    float gA, e1A, e2A, vA1, vA2;
    float gB, e1B, e2B, vB1, vB2;
    bool doneA, doneB;
    int itA, itB, obhA, obhB;

    auto grab = [&]() -> bool {
        int v = 0;
        if (gl == 0) v = atomicAdd(qhead, 2);
        v = __shfl(v, lead);
        if (v >= n) return false;
        const bool hasB = (v + 1) < n;
        sA = list[v]; tgA = tgt[v];
        const float vfA = vfb[v];
        float vfB;
        if (hasB) { sB = list[v + 1]; tgB = tgt[v + 1]; vfB = vfb[v + 1]; }
        else      { sB = sA;          tgB = tgA;        vfB = vfA; }
        fA0 = out[(size_t)sA * NN + gl];
        fA1 = out[(size_t)sA * NN + gl + 16];
        fB0 = out[(size_t)sB * NN + gl];
        fB1 = out[(size_t)sB * NN + gl + 16];
        fxr[gl]      = make_float2(fA0, fB0);
        fxr[gl + 16] = make_float2(fA1, fB1);
        wsync();
        n2A = 0.f; n2B = 0.f;
#pragma unroll
        for (int i = 0; i < NN; ++i) {
            const float2 q = fxr[i];
            n2A = fmaf(q.x, q.x, n2A);
            n2B = fmaf(q.y, q.y, n2B);
        }
#pragma unroll
        for (int j = 0; j < 8; ++j) { uA[j] = 0.f; uB[j] = 0.f; }
#pragma unroll
        for (int i = 0; i < NN; ++i) {
            const float2 q = fxr[i];
            const float4 wa = *(const float4*)(vW1 + i * HVD + k0);
            const float4 wb = *(const float4*)(vW1 + i * HVD + k0 + 4);
            uA[0] = fmaf(q.x, wa.x, uA[0]); uA[1] = fmaf(q.x, wa.y, uA[1]);
            uA[2] = fmaf(q.x, wa.z, uA[2]); uA[3] = fmaf(q.x, wa.w, uA[3]);
            uA[4] = fmaf(q.x, wb.x, uA[4]); uA[5] = fmaf(q.x, wb.y, uA[5]);
            uA[6] = fmaf(q.x, wb.z, uA[6]); uA[7] = fmaf(q.x, wb.w, uA[7]);
            uB[0] = fmaf(q.y, wa.x, uB[0]); uB[1] = fmaf(q.y, wa.y, uB[1]);
            uB[2] = fmaf(q.y, wa.z, uB[2]); uB[3] = fmaf(q.y, wa.w, uB[3]);
            uB[4] = fmaf(q.y, wb.x, uB[4]); uB[5] = fmaf(q.y, wb.y, uB[5]);
            uB[6] = fmaf(q.y, wb.z, uB[6]); uB[7] = fmaf(q.y, wb.w, uB[7]);
        }
        gA = sqrtf(tgA / vfA); e1A = 0.f; e2A = 1.f; vA1 = 0.f; vA2 = vfA;
        gB = sqrtf(tgB / vfB); e1B = 0.f; e2B = 1.f; vB1 = 0.f; vB2 = vfB;
        doneA = false; itA = 0; obhA = 0;
        doneB = !hasB; itB = 0; obhB = 0;
        return true;
    };
    if (!grab()) return;

    auto step = [&](bool& done, float& gamma, float& e1, float& e2,
                    float& v_e1, float& v_e2, int& it, int& obh,
                    const float vp, const float dv, const float target,
                    const int s, const float f0, const float f1) {
        if (done) return;
        // accept: at tolerance or bracket collapsed
        if (fabsf(vp - target) <= TOL_C || (e2 - e1) <= BRK_C) {
            out[(size_t)s * NN + gl]      = f0 * gamma;
            out[(size_t)s * NN + gl + 16] = f1 * gamma;
            done = true;
            return;
        }
        // ALWAYS contract the bracket with this eval.
        const float sa = sgn_(vp - target);
        const float s1 = sgn_(v_e1 - target);
        if (sa * s1 < 0.f) { e2 = gamma; v_e2 = vp; }
        else               { e1 = gamma; v_e1 = vp; }
        ++it;
        const float newt = gamma - (vp - target) / dv;
        if (it < FORCE_C && newt >= e1 && newt <= e2) {   // NaN fails -> bisect
            if (fabsf(newt - gamma) <= ACC_C) {
                // early accept: skip verification eval
                out[(size_t)s * NN + gl]      = f0 * newt;
                out[(size_t)s * NN + gl + 16] = f1 * newt;
                done = true;
                return;
            }
            gamma = newt;
        } else if (newt > e2 && e2 >= 1.0f) {
            // no-root band signature: root claimed above never-contracted e2=1
            if (++obh >= 2) {
                out[(size_t)s * NN + gl]      = f0;       // gamma = 1 exactly
                out[(size_t)s * NN + gl + 16] = f1;
                done = true;
                return;
            }
            gamma = 0.5f * (e1 + e2);                     // one confirming probe
        } else {
            gamma = 0.5f * (e1 + e2);                     // guaranteed shrink
        }
        if (it >= MAXIT_C) {
            out[(size_t)s * NN + gl]      = f0 * gamma;
            out[(size_t)s * NN + gl + 16] = f1 * gamma;
            done = true;
        }
    };

    for (;;) {
        float vpA, dvA, vpB, dvB;
        veval2_tan(gl, uA, uB, gA, gB, h1q, n2A, n2B,
                   b1v, b2v, d0c, w2s, w3s, vpA, dvA, vpB, dvB);
        step(doneA, gA, e1A, e2A, vA1, vA2, itA, obhA, vpA, dvA, tgA, sA, fA0, fA1);
        step(doneB, gB, e1B, e2B, vB1, vB2, itB, obhB, vpB, dvB, tgB, sB, fB0, fB1);
        if (doneA && doneB) {
            if (!grab()) break;
        }
    }
}

extern "C" void kernel_launch(void* const* d_in, const int* in_sizes, int n_in,
                              void* d_out, int out_size, void* d_ws, size_t ws_size,
                              hipStream_t stream)
{
    const float* x   = (const float*)d_in[0];
    const float* fW1 = (const float*)d_in[1];
    const float* fb1 = (const float*)d_in[2];
    const float* fW2 = (const float*)d_in[3];
    const float* fb2 = (const float*)d_in[4];
    const float* fW3 = (const float*)d_in[5];
    const float* fb3 = (const float*)d_in[6];
    const float* vW1 = (const float*)d_in[7];
    const float* vb1 = (const float*)d_in[8];
    const float* vW2 = (const float*)d_in[9];
    const float* vb2 = (const float*)d_in[10];
    const float* vW3 = (const float*)d_in[11];
    const float* vb3 = (const float*)d_in[12];
    float* out = (float*)d_out;

    char* ws = (char*)d_ws;
    int*   cnt   = (int*)ws;                                 // 4 B
    int*   qhead = (int*)(ws + 4);                           // 4 B
    float* h0g   = (float*)(ws + 64);                        // 8 floats
    int*   list  = (int*)(ws + 128);                         // BN ints
    float* tgt   = (float*)(ws + 128 + (size_t)BN * 4);      // BN floats
    float* vfb   = (float*)(ws + 128 + (size_t)BN * 8);      // BN floats
    unsigned short* w1b = (unsigned short*)(ws + 128 + (size_t)BN * 12);  // 8 KB (16B-aligned)
    unsigned short* w2b = w1b + HVD * NN;                    // 32 KB
    unsigned short* w3b = w2b + HVD * HVD;                   // 4 KB
    unsigned short* w2s = w3b + 16 * HVD;                    // 32 KB (solver, [k][col])
    unsigned short* w3s = w2s + HVD * HVD;                   // 2 KB  (solver, [k][c])

    hipMemsetAsync(ws, 0, 8, stream);                        // cnt + qhead

    hipLaunchKernelGGL(k_h0, dim3(1), dim3(HVD), 0, stream,
                       vb1, vW2, vb2, vW3, vb3, h0g);

    hipLaunchKernelGGL(k_wprep, dim3(32), dim3(256), 0, stream,
                       vW1, vW2, vW3, w1b, w2b, w3b, w2s, w3s);

    hipLaunchKernelGGL(k_setup, dim3(BN / (GPB * 2)), dim3(256), 0, stream,
                       x, fW1, fb1, fW2, fb2, fW3, fb3,
                       vb1, vb2, vb3, w1b, w2b, w3b,
                       h0g, out, cnt, list, tgt, vfb);

    hipLaunchKernelGGL(k_solve, dim3(NQBLK), dim3(64), 0, stream,
                       vW1, vb1, w2s, vb2, w3s, vb3,
                       h0g, out, cnt, list, tgt, vfb, qhead);
}